// Round 1
// baseline (784.578 us; speedup 1.0000x reference)
//
#include <hip/hip_runtime.h>
#include <math.h>

#define NB 4
#define NH 16
#define SS 2048
#define DD 64
#define BH (NB * NH)
#define QT 64
#define KT 64
#define NT 256
#define LSTR 68  // LDS row stride in floats (68*4B = 272B = 17*16B, keeps float4 align, rotates banks)
#define LOG2E 1.4426950408889634f

// ---------------- RoPE cos/sin table: tab[pos*32+j] = cos, tab[S*32 + pos*32+j] = sin
__global__ __launch_bounds__(NT) void rope_tab_kernel(float* __restrict__ tab) {
  int idx = blockIdx.x * NT + threadIdx.x;
  if (idx >= SS * 32) return;
  int pos = idx >> 5, j = idx & 31;
  double inv = pow(10000.0, -(double)j / 32.0);
  double ang = (double)pos * inv;
  tab[idx] = (float)cos(ang);
  tab[SS * 32 + idx] = (float)sin(ang);
}

__device__ __forceinline__ void get_cs(const float* __restrict__ tab, int pos, int j,
                                       float& c, float& s) {
  if (tab) {
    c = tab[pos * 32 + j];
    s = tab[SS * 32 + pos * 32 + j];
  } else {
    // fallback if workspace too small: inline trig
    float inv = exp2f(-(float)j * (13.287712379549449f / 32.0f));
    float ang = (float)pos * inv;
    c = cosf(ang);
    s = sinf(ang);
  }
}

// ---------------- fused RoPE + causal flash attention (fp32, VALU) ----------------
__global__ __launch_bounds__(NT, 3) void attn_kernel(
    const float* __restrict__ qg, const float* __restrict__ kg,
    const float* __restrict__ vg, float* __restrict__ og,
    const float* __restrict__ tab) {
  // KP is Ks during score phase, then reused as Ps (P tile) during PV phase.
  __shared__ __align__(16) float Qs[QT][LSTR];
  __shared__ __align__(16) float KP[KT][LSTR];
  __shared__ __align__(16) float Vt[DD][LSTR];  // V transposed: Vt[dv][kpos]

  const int tid = threadIdx.x;
  const int tx = tid & 15;   // 16 column-groups
  const int ty = tid >> 4;   // 16 row-groups (16 consecutive lanes per group -> shfl width 16)
  const int bid = blockIdx.x;
  const int nqt = SS / QT;                 // 32
  const int qt = nqt - 1 - (bid / BH);     // heavy q-tiles dispatched first
  const int bh = bid % BH;
  const int qbase = qt * QT;
  const size_t base = (size_t)bh * SS * DD;
  const float* Q = qg + base;
  const float* K = kg + base;
  const float* V = vg + base;
  float* O = og + base;

  // ---- stage Q tile with RoPE, fold in 1/sqrt(D) = 0.125
  const float scale = 0.125f;
  for (int t = 0; t < 8; ++t) {
    int idx = tid + t * NT;      // 0..2047 over (row 0..63, j 0..31)
    int r = idx >> 5, j = idx & 31;
    float c, s;
    get_cs(tab, qbase + r, j, c, s);
    float x1 = Q[(size_t)(qbase + r) * DD + j];
    float x2 = Q[(size_t)(qbase + r) * DD + j + 32];
    Qs[r][j]      = (x1 * c - x2 * s) * scale;
    Qs[r][j + 32] = (x1 * s + x2 * c) * scale;
  }

  float m_i[4], l_i[4], acc[4][4];
#pragma unroll
  for (int i = 0; i < 4; ++i) {
    m_i[i] = -INFINITY;
    l_i[i] = 0.f;
#pragma unroll
    for (int j = 0; j < 4; ++j) acc[i][j] = 0.f;
  }

  for (int kt = 0; kt <= qt; ++kt) {
    const int kbase = kt * KT;
    __syncthreads();  // previous tile's PV reads (KP-as-Ps, Vt) complete; Q staged on first iter

    // ---- stage K tile with RoPE into KP
    for (int t = 0; t < 8; ++t) {
      int idx = tid + t * NT;
      int r = idx >> 5, j = idx & 31;
      float c, s;
      get_cs(tab, kbase + r, j, c, s);
      float x1 = K[(size_t)(kbase + r) * DD + j];
      float x2 = K[(size_t)(kbase + r) * DD + j + 32];
      KP[r][j]      = x1 * c - x2 * s;
      KP[r][j + 32] = x1 * s + x2 * c;
    }
    // ---- stage V tile transposed
    for (int t = 0; t < 4; ++t) {
      int i4 = tid + t * NT;      // 0..1023 float4 slots over (row 0..63, col4 0..15)
      int r = i4 >> 4, c4 = (i4 & 15) * 4;
      const float4 v = *(const float4*)&V[(size_t)(kbase + r) * DD + c4];
      Vt[c4 + 0][r] = v.x;
      Vt[c4 + 1][r] = v.y;
      Vt[c4 + 2][r] = v.z;
      Vt[c4 + 3][r] = v.w;
    }
    __syncthreads();

    // ---- scores: sc[i][j] = rope(Q)[ty+16i] . rope(K)[tx+16j]  (scaled)
    float sc[4][4];
#pragma unroll
    for (int i = 0; i < 4; ++i)
#pragma unroll
      for (int j = 0; j < 4; ++j) sc[i][j] = 0.f;

    for (int d4 = 0; d4 < DD; d4 += 4) {
      float4 qv[4], kv[4];
#pragma unroll
      for (int i = 0; i < 4; ++i) qv[i] = *(const float4*)&Qs[ty + 16 * i][d4];
#pragma unroll
      for (int j = 0; j < 4; ++j) kv[j] = *(const float4*)&KP[tx + 16 * j][d4];
#pragma unroll
      for (int i = 0; i < 4; ++i)
#pragma unroll
        for (int j = 0; j < 4; ++j) {
          sc[i][j] += qv[i].x * kv[j].x;
          sc[i][j] += qv[i].y * kv[j].y;
          sc[i][j] += qv[i].z * kv[j].z;
          sc[i][j] += qv[i].w * kv[j].w;
        }
    }

    // ---- causal mask on the diagonal tile
    if (kt == qt) {
#pragma unroll
      for (int i = 0; i < 4; ++i)
#pragma unroll
        for (int j = 0; j < 4; ++j)
          if (kbase + tx + 16 * j > qbase + ty + 16 * i) sc[i][j] = -INFINITY;
    }

    __syncthreads();  // all score-phase reads of KP(Ks) done before overwriting as Ps

    // ---- online softmax; write P into KP
#pragma unroll
    for (int i = 0; i < 4; ++i) {
      float rm = fmaxf(fmaxf(sc[i][0], sc[i][1]), fmaxf(sc[i][2], sc[i][3]));
      rm = fmaxf(rm, __shfl_xor(rm, 1, 16));
      rm = fmaxf(rm, __shfl_xor(rm, 2, 16));
      rm = fmaxf(rm, __shfl_xor(rm, 4, 16));
      rm = fmaxf(rm, __shfl_xor(rm, 8, 16));
      float mn = fmaxf(m_i[i], rm);
      float al = exp2f((m_i[i] - mn) * LOG2E);  // exp2f(-inf)=0 handles first tile
      m_i[i] = mn;
      float rs = 0.f;
#pragma unroll
      for (int j = 0; j < 4; ++j) {
        float p = exp2f((sc[i][j] - mn) * LOG2E);
        KP[ty + 16 * i][tx + 16 * j] = p;
        rs += p;
      }
      rs += __shfl_xor(rs, 1, 16);
      rs += __shfl_xor(rs, 2, 16);
      rs += __shfl_xor(rs, 4, 16);
      rs += __shfl_xor(rs, 8, 16);
      l_i[i] = l_i[i] * al + rs;
#pragma unroll
      for (int j = 0; j < 4; ++j) acc[i][j] *= al;
    }
    __syncthreads();

    // ---- PV: acc[i][j] += P[ty+16i][:] . V[:][tx+16j]  (Vt rows are V columns)
    for (int k4 = 0; k4 < KT; k4 += 4) {
      float4 pv[4], vv[4];
#pragma unroll
      for (int i = 0; i < 4; ++i) pv[i] = *(const float4*)&KP[ty + 16 * i][k4];
#pragma unroll
      for (int j = 0; j < 4; ++j) vv[j] = *(const float4*)&Vt[tx + 16 * j][k4];
#pragma unroll
      for (int i = 0; i < 4; ++i)
#pragma unroll
        for (int j = 0; j < 4; ++j) {
          acc[i][j] += pv[i].x * vv[j].x;
          acc[i][j] += pv[i].y * vv[j].y;
          acc[i][j] += pv[i].z * vv[j].z;
          acc[i][j] += pv[i].w * vv[j].w;
        }
    }
  }

  // ---- epilogue: normalize and store
#pragma unroll
  for (int i = 0; i < 4; ++i) {
    float rinv = 1.0f / l_i[i];
#pragma unroll
    for (int j = 0; j < 4; ++j) {
      O[(size_t)(qbase + ty + 16 * i) * DD + tx + 16 * j] = acc[i][j] * rinv;
    }
  }
}

extern "C" void kernel_launch(void* const* d_in, const int* in_sizes, int n_in,
                              void* d_out, int out_size, void* d_ws, size_t ws_size,
                              hipStream_t stream) {
  const float* q = (const float*)d_in[0];
  const float* k = (const float*)d_in[1];
  const float* v = (const float*)d_in[2];
  // d_in[3] is the causal mask; causality is computed analytically.
  float* out = (float*)d_out;

  float* tab = nullptr;
  const size_t tab_bytes = (size_t)2 * SS * 32 * sizeof(float);  // 512 KB
  if (ws_size >= tab_bytes) {
    tab = (float*)d_ws;
    rope_tab_kernel<<<(SS * 32 + NT - 1) / NT, NT, 0, stream>>>(tab);
  }

  attn_kernel<<<dim3(BH * (SS / QT)), dim3(NT), 0, stream>>>(q, k, v, out, tab);
}

// Round 2
// 391.953 us; speedup vs baseline: 2.0017x; 2.0017x over previous
//
#include <hip/hip_runtime.h>
#include <hip/hip_bf16.h>
#include <math.h>

#define NB 4
#define NH 16
#define SS 2048
#define DD 64
#define BH (NB * NH)
#define QT 64
#define KT 64
#define NT 256
#define LQ 72   // LDS row stride in bf16 elements (144 B) -> 2-way bank alias on b128 frag reads (free)
#define LOG2E 1.4426950408889634f

typedef __attribute__((ext_vector_type(8))) short s8v;
typedef __attribute__((ext_vector_type(4))) float f4v;

// ---------------- RoPE cos/sin table: tab[pos*32+j] = cos, tab[S*32 + pos*32+j] = sin
__global__ __launch_bounds__(NT) void rope_tab_kernel(float* __restrict__ tab) {
  int idx = blockIdx.x * NT + threadIdx.x;
  if (idx >= SS * 32) return;
  int pos = idx >> 5, j = idx & 31;
  double inv = pow(10000.0, -(double)j / 32.0);
  double ang = (double)pos * inv;
  tab[idx] = (float)cos(ang);
  tab[SS * 32 + idx] = (float)sin(ang);
}

__device__ __forceinline__ void get_cs(const float* __restrict__ tab, int pos, int j,
                                       float& c, float& s) {
  if (tab) {
    c = tab[pos * 32 + j];
    s = tab[SS * 32 + pos * 32 + j];
  } else {
    float inv = exp2f(-(float)j * (13.287712379549449f / 32.0f));
    float ang = (float)pos * inv;
    c = cosf(ang);
    s = sinf(ang);
  }
}

__device__ __forceinline__ short f2b(float x) {
  __hip_bfloat16 h = __float2bfloat16(x);
  return *reinterpret_cast<short*>(&h);
}

// ---------------- fused RoPE + causal flash attention (bf16 MFMA) ----------------
__global__ __launch_bounds__(NT, 4) void attn_kernel(
    const float* __restrict__ qg, const float* __restrict__ kg,
    const float* __restrict__ vg, float* __restrict__ og,
    const float* __restrict__ tab) {
  __shared__ __align__(16) short Qs[QT * LQ];       // rope(Q)*0.125*log2e, bf16
  __shared__ __align__(16) short Ks[KT * LQ];       // rope(K), bf16
  __shared__ __align__(16) short Vt[DD * LQ];       // V transposed: Vt[d][kpos]
  __shared__ __align__(16) short Ps[4][16 * LQ];    // per-wave P tile (16 rows x 64 cols)

  const int tid = threadIdx.x;
  const int lane = tid & 63;
  const int wv = tid >> 6;       // wave 0..3, owns Q rows wv*16..wv*16+15
  const int quad = lane >> 4;    // 0..3
  const int lx = lane & 15;      // 0..15

  const int bid = blockIdx.x;
  const int qt = (SS / QT) - 1 - (bid >> 6);   // heavy q-tiles first
  const int bh = bid & 63;
  const int qbase = qt * QT;
  const size_t base = (size_t)bh * SS * DD;
  const float* Q = qg + base;
  const float* K = kg + base;
  const float* V = vg + base;
  float* O = og + base;

  // ---- stage Q tile: RoPE, fold 0.125*log2e, bf16
  const float qscale = 0.125f * LOG2E;
  for (int t = 0; t < 8; ++t) {
    int idx = tid + t * NT;
    int r = idx >> 5, j = idx & 31;
    float c, s;
    get_cs(tab, qbase + r, j, c, s);
    float x1 = Q[(size_t)(qbase + r) * DD + j];
    float x2 = Q[(size_t)(qbase + r) * DD + j + 32];
    Qs[r * LQ + j]      = f2b((x1 * c - x2 * s) * qscale);
    Qs[r * LQ + j + 32] = f2b((x1 * s + x2 * c) * qscale);
  }
  __syncthreads();

  // ---- Q fragments (A-layout), K-loop invariant
  s8v qf0 = *(const s8v*)&Qs[(wv * 16 + lx) * LQ + quad * 8];
  s8v qf1 = *(const s8v*)&Qs[(wv * 16 + lx) * LQ + 32 + quad * 8];

  float m_[4], l_[4];
  f4v o_[4];
#pragma unroll
  for (int r = 0; r < 4; ++r) { m_[r] = -INFINITY; l_[r] = 0.f; }
#pragma unroll
  for (int db = 0; db < 4; ++db) o_[db] = (f4v){0.f, 0.f, 0.f, 0.f};

  for (int kt = 0; kt <= qt; ++kt) {
    const int kbase = kt * KT;
    __syncthreads();  // prev iter's Ks/Vt reads done (also covers initial Qs reads)

    // ---- stage K tile (RoPE, bf16)
    for (int t = 0; t < 8; ++t) {
      int idx = tid + t * NT;
      int r = idx >> 5, j = idx & 31;
      float c, s;
      get_cs(tab, kbase + r, j, c, s);
      float x1 = K[(size_t)(kbase + r) * DD + j];
      float x2 = K[(size_t)(kbase + r) * DD + j + 32];
      Ks[r * LQ + j]      = f2b(x1 * c - x2 * s);
      Ks[r * LQ + j + 32] = f2b(x1 * s + x2 * c);
    }
    // ---- stage V tile transposed (bf16)
    for (int t = 0; t < 4; ++t) {
      int i4 = tid + t * NT;
      int r = i4 >> 4, c4 = (i4 & 15) * 4;
      const float4 v = *(const float4*)&V[(size_t)(kbase + r) * DD + c4];
      Vt[(c4 + 0) * LQ + r] = f2b(v.x);
      Vt[(c4 + 1) * LQ + r] = f2b(v.y);
      Vt[(c4 + 2) * LQ + r] = f2b(v.z);
      Vt[(c4 + 3) * LQ + r] = f2b(v.w);
    }
    __syncthreads();

    // ---- scores: S[16x64] per wave via MFMA; sc[nb][reg]: row=quad*4+reg, col=nb*16+lx
    f4v sc[4];
#pragma unroll
    for (int nb = 0; nb < 4; ++nb) {
      s8v kf0 = *(const s8v*)&Ks[(nb * 16 + lx) * LQ + quad * 8];
      s8v kf1 = *(const s8v*)&Ks[(nb * 16 + lx) * LQ + 32 + quad * 8];
      f4v z = (f4v){0.f, 0.f, 0.f, 0.f};
      z = __builtin_amdgcn_mfma_f32_16x16x32_bf16(qf0, kf0, z, 0, 0, 0);
      z = __builtin_amdgcn_mfma_f32_16x16x32_bf16(qf1, kf1, z, 0, 0, 0);
      sc[nb] = z;
    }

    // ---- causal mask (diagonal tile only; scores are in log2 units)
    if (kt == qt) {
#pragma unroll
      for (int nb = 0; nb < 4; ++nb)
#pragma unroll
        for (int r = 0; r < 4; ++r)
          if (kbase + nb * 16 + lx > qbase + wv * 16 + quad * 4 + r)
            sc[nb][r] = -INFINITY;
    }

    // ---- online softmax (base-2); write P (bf16) to this wave's Ps region
#pragma unroll
    for (int r = 0; r < 4; ++r) {
      float mx = fmaxf(fmaxf(sc[0][r], sc[1][r]), fmaxf(sc[2][r], sc[3][r]));
      mx = fmaxf(mx, __shfl_xor(mx, 1, 16));
      mx = fmaxf(mx, __shfl_xor(mx, 2, 16));
      mx = fmaxf(mx, __shfl_xor(mx, 4, 16));
      mx = fmaxf(mx, __shfl_xor(mx, 8, 16));
      float mn = fmaxf(m_[r], mx);
      float al = __builtin_amdgcn_exp2f(m_[r] - mn);  // exp2(-inf)=0 on first tile
      m_[r] = mn;
      float rs = 0.f;
#pragma unroll
      for (int nb = 0; nb < 4; ++nb) {
        float p = __builtin_amdgcn_exp2f(sc[nb][r] - mn);
        rs += p;
        Ps[wv][(quad * 4 + r) * LQ + nb * 16 + lx] = f2b(p);
      }
      rs += __shfl_xor(rs, 1, 16);
      rs += __shfl_xor(rs, 2, 16);
      rs += __shfl_xor(rs, 4, 16);
      rs += __shfl_xor(rs, 8, 16);
      l_[r] = l_[r] * al + rs;
      o_[0][r] *= al; o_[1][r] *= al; o_[2][r] *= al; o_[3][r] *= al;
    }
    // no barrier: each wave reads only its own Ps region (lgkmcnt ordering suffices)

    // ---- PV: O[16x64] += P[16x64] . V[64x64]
    s8v pf0 = *(const s8v*)&Ps[wv][lx * LQ + quad * 8];
    s8v pf1 = *(const s8v*)&Ps[wv][lx * LQ + 32 + quad * 8];
#pragma unroll
    for (int db = 0; db < 4; ++db) {
      s8v vf0 = *(const s8v*)&Vt[(db * 16 + lx) * LQ + quad * 8];
      s8v vf1 = *(const s8v*)&Vt[(db * 16 + lx) * LQ + 32 + quad * 8];
      o_[db] = __builtin_amdgcn_mfma_f32_16x16x32_bf16(pf0, vf0, o_[db], 0, 0, 0);
      o_[db] = __builtin_amdgcn_mfma_f32_16x16x32_bf16(pf1, vf1, o_[db], 0, 0, 0);
    }
  }

  // ---- epilogue: normalize, store fp32
#pragma unroll
  for (int r = 0; r < 4; ++r) {
    float rinv = 1.0f / l_[r];
    int row = qbase + wv * 16 + quad * 4 + r;
#pragma unroll
    for (int db = 0; db < 4; ++db)
      O[(size_t)row * DD + db * 16 + lx] = o_[db][r] * rinv;
  }
}

extern "C" void kernel_launch(void* const* d_in, const int* in_sizes, int n_in,
                              void* d_out, int out_size, void* d_ws, size_t ws_size,
                              hipStream_t stream) {
  const float* q = (const float*)d_in[0];
  const float* k = (const float*)d_in[1];
  const float* v = (const float*)d_in[2];
  float* out = (float*)d_out;

  float* tab = nullptr;
  const size_t tab_bytes = (size_t)2 * SS * 32 * sizeof(float);  // 512 KB
  if (ws_size >= tab_bytes) {
    tab = (float*)d_ws;
    rope_tab_kernel<<<(SS * 32 + NT - 1) / NT, NT, 0, stream>>>(tab);
  }

  attn_kernel<<<dim3(BH * (SS / QT)), dim3(NT), 0, stream>>>(q, k, v, out, tab);
}

// Round 3
// 263.482 us; speedup vs baseline: 2.9777x; 1.4876x over previous
//
#include <hip/hip_runtime.h>
#include <hip/hip_bf16.h>
#include <math.h>

#define NB 4
#define NH 16
#define SS 2048
#define DD 64
#define BH (NB * NH)   // 64
#define QT 64
#define KT 64
#define NT 256
#define NKT (SS / KT)  // 32
#define LQ 72          // padded stride (shorts) for Ps only
#define LOG2E 1.4426950408889634f

typedef __attribute__((ext_vector_type(8))) short s8v;
typedef __attribute__((ext_vector_type(4))) float f4v;

__device__ __forceinline__ short f2b(float x) {
  __hip_bfloat16 h = __float2bfloat16(x);
  return *reinterpret_cast<short*>(&h);
}

// async global->LDS, 16B per lane; dest = wave-uniform base + lane*16
__device__ __forceinline__ void gload16(const void* g, void* l) {
  __builtin_amdgcn_global_load_lds(
      (const __attribute__((address_space(1))) void*)g,
      (__attribute__((address_space(3))) void*)l, 16, 0, 0);
}

// ---------------- RoPE cos/sin table ----------------
__global__ __launch_bounds__(NT) void rope_tab_kernel(float* __restrict__ tab) {
  int idx = blockIdx.x * NT + threadIdx.x;
  if (idx >= SS * 32) return;
  int pos = idx >> 5, j = idx & 31;
  double inv = pow(10000.0, -(double)j / 32.0);
  double ang = (double)pos * inv;
  tab[idx] = (float)cos(ang);
  tab[SS * 32 + idx] = (float)sin(ang);
}

__device__ __forceinline__ void get_cs(const float* __restrict__ tab, int pos, int j,
                                       float& c, float& s) {
  if (tab) {
    c = tab[pos * 32 + j];
    s = tab[SS * 32 + pos * 32 + j];
  } else {
    float inv = exp2f(-(float)j * (13.287712379549449f / 32.0f));
    float ang = (float)pos * inv;
    c = cosf(ang);
    s = sinf(ang);
  }
}

// ---------------- prep: rope(K) -> bf16, natural [h][s][d] layout ----------------
__global__ __launch_bounds__(NT) void prep_k_kernel(const float* __restrict__ kg,
                                                    const float* __restrict__ tab,
                                                    short* __restrict__ kr) {
  int idx = blockIdx.x * NT + threadIdx.x;   // over 64*2048*32
  int row = idx >> 5, j = idx & 31;
  int pos = row & (SS - 1);
  float c = tab[pos * 32 + j], s = tab[SS * 32 + pos * 32 + j];
  size_t o = (size_t)row * DD + j;
  float x1 = kg[o], x2 = kg[o + 32];
  kr[o] = f2b(x1 * c - x2 * s);
  kr[o + 32] = f2b(x1 * s + x2 * c);
}

// ---------------- prep: V^T bf16, packed tiles [h][kt][d][64] ----------------
__global__ __launch_bounds__(NT) void prep_v_kernel(const float* __restrict__ vg,
                                                    short* __restrict__ vt) {
  __shared__ float Vs[KT][DD + 1];
  int b = blockIdx.x;                       // h*32 + kt
  int h = b >> 5, kt = b & 31;
  const float* vtile = vg + ((size_t)h * SS + (size_t)kt * KT) * DD;
  int t = threadIdx.x;
#pragma unroll
  for (int i = 0; i < 4; ++i) {
    int s = t + i * NT;                     // 1024 float4 slots
    int r = s >> 4, c4 = (s & 15) * 4;
    float4 v = *(const float4*)&vtile[(size_t)r * DD + c4];
    Vs[r][c4 + 0] = v.x;
    Vs[r][c4 + 1] = v.y;
    Vs[r][c4 + 2] = v.z;
    Vs[r][c4 + 3] = v.w;
  }
  __syncthreads();
  short* otile = vt + (size_t)b * (DD * KT);
#pragma unroll
  for (int i = 0; i < 2; ++i) {
    int c = t + i * NT;                     // 512 short8 chunks
    int d = c >> 3, k8 = (c & 7) * 8;
    s8v o;
#pragma unroll
    for (int u = 0; u < 8; ++u) o[u] = f2b(Vs[k8 + u][d]);
    *(s8v*)&otile[d * KT + k8] = o;
  }
}

// ---------------- fast attention: async-staged bf16 MFMA ----------------
__global__ __launch_bounds__(NT, 4) void attn_fast(
    const float* __restrict__ qg, const short* __restrict__ kr,
    const short* __restrict__ vt, float* __restrict__ og,
    const float* __restrict__ tab) {
  // unpadded, XOR-swizzled: phys chunk p of row r holds logical chunk p^(r&7)
  __shared__ __align__(16) short Qs[QT * DD];
  __shared__ __align__(16) short Ks[KT * DD];
  __shared__ __align__(16) short Vts[DD * KT];
  __shared__ __align__(16) short Ps[4][16 * LQ];

  const int tid = threadIdx.x;
  const int lane = tid & 63;
  const int wv = tid >> 6;
  const int quad = lane >> 4;
  const int lx = lane & 15;
  const int xb = lx & 7;                          // row&7 for all frag rows (rows = n*16+lx)
  const int foff0 = ((quad ^ xb) << 3);           // frag chunk offsets (shorts), row-invariant
  const int foff1 = (((quad | 4) ^ xb) << 3);

  const int bid = blockIdx.x;
  const int qt = NKT - 1 - (bid >> 6);            // heavy q-tiles first
  const int bh = bid & 63;
  const int qbase = qt * QT;
  const float* Q = qg + (size_t)bh * SS * DD;
  float* O = og + (size_t)bh * SS * DD;
  const short* krh = kr + (size_t)bh * SS * DD;
  const short* vth = vt + (size_t)bh * NKT * (DD * KT);

  // ---- stage Q: rope * 0.125*log2e -> bf16 -> swizzled LDS
  const float qscale = 0.125f * LOG2E;
  for (int t = 0; t < 8; ++t) {
    int idx = tid + t * NT;
    int r = idx >> 5, j = idx & 31;
    float c, s;
    get_cs(tab, qbase + r, j, c, s);
    float x1 = Q[(size_t)(qbase + r) * DD + j];
    float x2 = Q[(size_t)(qbase + r) * DD + j + 32];
    int rb = r & 7;
    Qs[r * DD + ((((j >> 3) ^ rb) << 3) | (j & 7))] = f2b((x1 * c - x2 * s) * qscale);
    Qs[r * DD + (((((j >> 3) | 4) ^ rb) << 3) | (j & 7))] = f2b((x1 * s + x2 * c) * qscale);
  }
  __syncthreads();

  const int rq = wv * 16 + lx;
  s8v qf0 = *(const s8v*)&Qs[rq * DD + foff0];
  s8v qf1 = *(const s8v*)&Qs[rq * DD + foff1];

  float m_[4], l_[4];
  f4v o_[4];
#pragma unroll
  for (int r = 0; r < 4; ++r) { m_[r] = -INFINITY; l_[r] = 0.f; }
#pragma unroll
  for (int db = 0; db < 4; ++db) o_[db] = (f4v){0.f, 0.f, 0.f, 0.f};

  for (int kt = 0; kt <= qt; ++kt) {
    const int kbase = kt * KT;
    const short* ktile = krh + (size_t)kbase * DD;
    const short* vtile = vth + (size_t)kt * (DD * KT);
    __syncthreads();  // prev iter's LDS reads done

    // ---- async stage K and V^T tiles (swizzled via source permutation)
#pragma unroll
    for (int i = 0; i < 2; ++i) {
      int c = wv * 128 + i * 64 + lane;           // phys chunk
      int r = c >> 3, qp = c & 7;
      int qs = qp ^ (r & 7);                      // logical source chunk
      gload16(ktile + r * DD + qs * 8, &Ks[(wv * 128 + i * 64) * 8]);
      gload16(vtile + r * DD + qs * 8, &Vts[(wv * 128 + i * 64) * 8]);
    }
    __syncthreads();  // drains vmcnt: tiles resident

    // ---- scores S[16x64] per wave
    f4v sc[4];
#pragma unroll
    for (int nb = 0; nb < 4; ++nb) {
      const int rk = nb * 16 + lx;
      s8v kf0 = *(const s8v*)&Ks[rk * DD + foff0];
      s8v kf1 = *(const s8v*)&Ks[rk * DD + foff1];
      f4v z = (f4v){0.f, 0.f, 0.f, 0.f};
      z = __builtin_amdgcn_mfma_f32_16x16x32_bf16(qf0, kf0, z, 0, 0, 0);
      z = __builtin_amdgcn_mfma_f32_16x16x32_bf16(qf1, kf1, z, 0, 0, 0);
      sc[nb] = z;
    }

    if (kt == qt) {
#pragma unroll
      for (int nb = 0; nb < 4; ++nb)
#pragma unroll
        for (int r = 0; r < 4; ++r)
          if (kbase + nb * 16 + lx > qbase + wv * 16 + quad * 4 + r)
            sc[nb][r] = -INFINITY;
    }

    // ---- online softmax (base-2); P bf16 into this wave's Ps
#pragma unroll
    for (int r = 0; r < 4; ++r) {
      float mx = fmaxf(fmaxf(sc[0][r], sc[1][r]), fmaxf(sc[2][r], sc[3][r]));
      mx = fmaxf(mx, __shfl_xor(mx, 1, 16));
      mx = fmaxf(mx, __shfl_xor(mx, 2, 16));
      mx = fmaxf(mx, __shfl_xor(mx, 4, 16));
      mx = fmaxf(mx, __shfl_xor(mx, 8, 16));
      float mn = fmaxf(m_[r], mx);
      float al = __builtin_amdgcn_exp2f(m_[r] - mn);
      m_[r] = mn;
      float rs = 0.f;
#pragma unroll
      for (int nb = 0; nb < 4; ++nb) {
        float p = __builtin_amdgcn_exp2f(sc[nb][r] - mn);
        rs += p;
        Ps[wv][(quad * 4 + r) * LQ + nb * 16 + lx] = f2b(p);
      }
      rs += __shfl_xor(rs, 1, 16);
      rs += __shfl_xor(rs, 2, 16);
      rs += __shfl_xor(rs, 4, 16);
      rs += __shfl_xor(rs, 8, 16);
      l_[r] = l_[r] * al + rs;
      o_[0][r] *= al; o_[1][r] *= al; o_[2][r] *= al; o_[3][r] *= al;
    }
    // no barrier: wave reads only its own Ps region

    // ---- PV
    s8v pf0 = *(const s8v*)&Ps[wv][lx * LQ + quad * 8];
    s8v pf1 = *(const s8v*)&Ps[wv][lx * LQ + 32 + quad * 8];
#pragma unroll
    for (int db = 0; db < 4; ++db) {
      const int rv = db * 16 + lx;
      s8v vf0 = *(const s8v*)&Vts[rv * KT + foff0];
      s8v vf1 = *(const s8v*)&Vts[rv * KT + foff1];
      o_[db] = __builtin_amdgcn_mfma_f32_16x16x32_bf16(pf0, vf0, o_[db], 0, 0, 0);
      o_[db] = __builtin_amdgcn_mfma_f32_16x16x32_bf16(pf1, vf1, o_[db], 0, 0, 0);
    }
  }

#pragma unroll
  for (int r = 0; r < 4; ++r) {
    float rinv = 1.0f / l_[r];
    int row = qbase + wv * 16 + quad * 4 + r;
#pragma unroll
    for (int db = 0; db < 4; ++db)
      O[(size_t)row * DD + db * 16 + lx] = o_[db][r] * rinv;
  }
}

// ---------------- fallback (round-2 proven path, used if ws too small) ----------------
__global__ __launch_bounds__(NT, 4) void attn_fallback(
    const float* __restrict__ qg, const float* __restrict__ kg,
    const float* __restrict__ vg, float* __restrict__ og,
    const float* __restrict__ tab) {
  __shared__ __align__(16) short Qs[QT * LQ];
  __shared__ __align__(16) short Ks[KT * LQ];
  __shared__ __align__(16) short Vt[DD * LQ];
  __shared__ __align__(16) short Ps[4][16 * LQ];

  const int tid = threadIdx.x;
  const int lane = tid & 63;
  const int wv = tid >> 6;
  const int quad = lane >> 4;
  const int lx = lane & 15;

  const int bid = blockIdx.x;
  const int qt = NKT - 1 - (bid >> 6);
  const int bh = bid & 63;
  const int qbase = qt * QT;
  const size_t base = (size_t)bh * SS * DD;
  const float* Q = qg + base;
  const float* K = kg + base;
  const float* V = vg + base;
  float* O = og + base;

  const float qscale = 0.125f * LOG2E;
  for (int t = 0; t < 8; ++t) {
    int idx = tid + t * NT;
    int r = idx >> 5, j = idx & 31;
    float c, s;
    get_cs(tab, qbase + r, j, c, s);
    float x1 = Q[(size_t)(qbase + r) * DD + j];
    float x2 = Q[(size_t)(qbase + r) * DD + j + 32];
    Qs[r * LQ + j] = f2b((x1 * c - x2 * s) * qscale);
    Qs[r * LQ + j + 32] = f2b((x1 * s + x2 * c) * qscale);
  }
  __syncthreads();

  s8v qf0 = *(const s8v*)&Qs[(wv * 16 + lx) * LQ + quad * 8];
  s8v qf1 = *(const s8v*)&Qs[(wv * 16 + lx) * LQ + 32 + quad * 8];

  float m_[4], l_[4];
  f4v o_[4];
#pragma unroll
  for (int r = 0; r < 4; ++r) { m_[r] = -INFINITY; l_[r] = 0.f; }
#pragma unroll
  for (int db = 0; db < 4; ++db) o_[db] = (f4v){0.f, 0.f, 0.f, 0.f};

  for (int kt = 0; kt <= qt; ++kt) {
    const int kbase = kt * KT;
    __syncthreads();
    for (int t = 0; t < 8; ++t) {
      int idx = tid + t * NT;
      int r = idx >> 5, j = idx & 31;
      float c, s;
      get_cs(tab, kbase + r, j, c, s);
      float x1 = K[(size_t)(kbase + r) * DD + j];
      float x2 = K[(size_t)(kbase + r) * DD + j + 32];
      Ks[r * LQ + j] = f2b(x1 * c - x2 * s);
      Ks[r * LQ + j + 32] = f2b(x1 * s + x2 * c);
    }
    for (int t = 0; t < 4; ++t) {
      int i4 = tid + t * NT;
      int r = i4 >> 4, c4 = (i4 & 15) * 4;
      const float4 v = *(const float4*)&V[(size_t)(kbase + r) * DD + c4];
      Vt[(c4 + 0) * LQ + r] = f2b(v.x);
      Vt[(c4 + 1) * LQ + r] = f2b(v.y);
      Vt[(c4 + 2) * LQ + r] = f2b(v.z);
      Vt[(c4 + 3) * LQ + r] = f2b(v.w);
    }
    __syncthreads();

    f4v sc[4];
#pragma unroll
    for (int nb = 0; nb < 4; ++nb) {
      s8v kf0 = *(const s8v*)&Ks[(nb * 16 + lx) * LQ + quad * 8];
      s8v kf1 = *(const s8v*)&Ks[(nb * 16 + lx) * LQ + 32 + quad * 8];
      f4v z = (f4v){0.f, 0.f, 0.f, 0.f};
      z = __builtin_amdgcn_mfma_f32_16x16x32_bf16(qf0, kf0, z, 0, 0, 0);
      z = __builtin_amdgcn_mfma_f32_16x16x32_bf16(qf1, kf1, z, 0, 0, 0);
      sc[nb] = z;
    }
    if (kt == qt) {
#pragma unroll
      for (int nb = 0; nb < 4; ++nb)
#pragma unroll
        for (int r = 0; r < 4; ++r)
          if (kbase + nb * 16 + lx > qbase + wv * 16 + quad * 4 + r)
            sc[nb][r] = -INFINITY;
    }
#pragma unroll
    for (int r = 0; r < 4; ++r) {
      float mx = fmaxf(fmaxf(sc[0][r], sc[1][r]), fmaxf(sc[2][r], sc[3][r]));
      mx = fmaxf(mx, __shfl_xor(mx, 1, 16));
      mx = fmaxf(mx, __shfl_xor(mx, 2, 16));
      mx = fmaxf(mx, __shfl_xor(mx, 4, 16));
      mx = fmaxf(mx, __shfl_xor(mx, 8, 16));
      float mn = fmaxf(m_[r], mx);
      float al = __builtin_amdgcn_exp2f(m_[r] - mn);
      m_[r] = mn;
      float rs = 0.f;
#pragma unroll
      for (int nb = 0; nb < 4; ++nb) {
        float p = __builtin_amdgcn_exp2f(sc[nb][r] - mn);
        rs += p;
        Ps[wv][(quad * 4 + r) * LQ + nb * 16 + lx] = f2b(p);
      }
      rs += __shfl_xor(rs, 1, 16);
      rs += __shfl_xor(rs, 2, 16);
      rs += __shfl_xor(rs, 4, 16);
      rs += __shfl_xor(rs, 8, 16);
      l_[r] = l_[r] * al + rs;
      o_[0][r] *= al; o_[1][r] *= al; o_[2][r] *= al; o_[3][r] *= al;
    }
    s8v pf0 = *(const s8v*)&Ps[wv][lx * LQ + quad * 8];
    s8v pf1 = *(const s8v*)&Ps[wv][lx * LQ + 32 + quad * 8];
#pragma unroll
    for (int db = 0; db < 4; ++db) {
      s8v vf0 = *(const s8v*)&Vt[(db * 16 + lx) * LQ + quad * 8];
      s8v vf1 = *(const s8v*)&Vt[(db * 16 + lx) * LQ + 32 + quad * 8];
      o_[db] = __builtin_amdgcn_mfma_f32_16x16x32_bf16(pf0, vf0, o_[db], 0, 0, 0);
      o_[db] = __builtin_amdgcn_mfma_f32_16x16x32_bf16(pf1, vf1, o_[db], 0, 0, 0);
    }
  }
#pragma unroll
  for (int r = 0; r < 4; ++r) {
    float rinv = 1.0f / l_[r];
    int row = qbase + wv * 16 + quad * 4 + r;
#pragma unroll
    for (int db = 0; db < 4; ++db)
      O[(size_t)row * DD + db * 16 + lx] = o_[db][r] * rinv;
  }
}

extern "C" void kernel_launch(void* const* d_in, const int* in_sizes, int n_in,
                              void* d_out, int out_size, void* d_ws, size_t ws_size,
                              hipStream_t stream) {
  const float* q = (const float*)d_in[0];
  const float* k = (const float*)d_in[1];
  const float* v = (const float*)d_in[2];
  float* out = (float*)d_out;

  const size_t tab_bytes = (size_t)2 * SS * 32 * sizeof(float);          // 512 KB
  const size_t kr_bytes = (size_t)BH * SS * DD * sizeof(short);          // 16 MB
  const size_t vt_bytes = kr_bytes;                                      // 16 MB
  const size_t need = tab_bytes + kr_bytes + vt_bytes;

  if (ws_size >= need) {
    float* tab = (float*)d_ws;
    short* kr = (short*)((char*)d_ws + tab_bytes);
    short* vt = (short*)((char*)d_ws + tab_bytes + kr_bytes);
    rope_tab_kernel<<<(SS * 32 + NT - 1) / NT, NT, 0, stream>>>(tab);
    prep_k_kernel<<<(BH * SS * 32) / NT, NT, 0, stream>>>(k, tab, kr);
    prep_v_kernel<<<BH * NKT, NT, 0, stream>>>(v, vt);
    attn_fast<<<dim3(BH * (SS / QT)), dim3(NT), 0, stream>>>(q, kr, vt, out, tab);
  } else {
    float* tab = nullptr;
    if (ws_size >= tab_bytes) {
      tab = (float*)d_ws;
      rope_tab_kernel<<<(SS * 32 + NT - 1) / NT, NT, 0, stream>>>(tab);
    }
    attn_fallback<<<dim3(BH * (SS / QT)), dim3(NT), 0, stream>>>(q, k, v, out, tab);
  }
}

// Round 4
// 244.748 us; speedup vs baseline: 3.2057x; 1.0765x over previous
//
#include <hip/hip_runtime.h>
#include <hip/hip_bf16.h>
#include <math.h>

#define SS 2048
#define DD 64
#define BH 64          // B*H
#define QT 64
#define KT 64
#define NT 256
#define NKT (SS / KT)  // 32
#define LQ 72          // padded stride (shorts), fallback kernel only
#define LOG2E 1.4426950408889634f

typedef __attribute__((ext_vector_type(8))) short s8v;
typedef __attribute__((ext_vector_type(4))) float f4v;

__device__ __forceinline__ short f2b(float x) {
  __hip_bfloat16 h = __float2bfloat16(x);
  return *reinterpret_cast<short*>(&h);
}

// async global->LDS, 16B per lane; dest = wave-uniform base + lane*16
__device__ __forceinline__ void gload16(const void* g, void* l) {
  __builtin_amdgcn_global_load_lds(
      (const __attribute__((address_space(1))) void*)g,
      (__attribute__((address_space(3))) void*)l, 16, 0, 0);
}

// ---------------- RoPE cos/sin table (fp32: matches reference's fp32 angles) ----
__global__ __launch_bounds__(NT) void rope_tab_kernel(float* __restrict__ tab) {
  int idx = blockIdx.x * NT + threadIdx.x;
  if (idx >= SS * 32) return;
  int pos = idx >> 5, j = idx & 31;
  float inv = exp2f(-(float)j * (13.287712379549449f / 32.0f));  // 10000^(-j/32)
  float ang = (float)pos * inv;
  float s, c;
  sincosf(ang, &s, &c);  // accurate variant (proper range reduction for ang up to 2047)
  tab[idx] = c;
  tab[SS * 32 + idx] = s;
}

__device__ __forceinline__ void get_cs(const float* __restrict__ tab, int pos, int j,
                                       float& c, float& s) {
  if (tab) {
    c = tab[pos * 32 + j];
    s = tab[SS * 32 + pos * 32 + j];
  } else {
    float inv = exp2f(-(float)j * (13.287712379549449f / 32.0f));
    float ang = (float)pos * inv;
    sincosf(ang, &s, &c);
  }
}

// ---------------- fused prep: rope(K)->bf16 [h][s][d]; V^T bf16 tiles [h][kt][d][64]
__global__ __launch_bounds__(NT) void prep_kv_kernel(
    const float* __restrict__ kg, const float* __restrict__ vg,
    const float* __restrict__ tab, short* __restrict__ kr, short* __restrict__ vt) {
  __shared__ float Vs[KT][DD + 1];
  const int b = blockIdx.x;  // h*32 + kt
  const int kt = b & 31;
  const int t = threadIdx.x;
  const size_t ofs = (size_t)b * (KT * DD);  // (h*SS + kt*KT)*DD == b*4096
  const float* ktile = kg + ofs;
  short* krt = kr + ofs;

  // K: rope + bf16
#pragma unroll
  for (int i = 0; i < 8; ++i) {
    int idx = t + i * NT;  // 2048 (row, j) pairs
    int r = idx >> 5, j = idx & 31;
    int pos = kt * KT + r;
    float c = tab[pos * 32 + j], s = tab[SS * 32 + pos * 32 + j];
    float x1 = ktile[r * DD + j], x2 = ktile[r * DD + j + 32];
    krt[r * DD + j] = f2b(x1 * c - x2 * s);
    krt[r * DD + j + 32] = f2b(x1 * s + x2 * c);
  }

  // V: transpose via LDS, bf16
  const float* vtile = vg + ofs;
#pragma unroll
  for (int i = 0; i < 4; ++i) {
    int s4 = t + i * NT;
    int r = s4 >> 4, c4 = (s4 & 15) * 4;
    float4 v = *(const float4*)&vtile[r * DD + c4];
    Vs[r][c4 + 0] = v.x;
    Vs[r][c4 + 1] = v.y;
    Vs[r][c4 + 2] = v.z;
    Vs[r][c4 + 3] = v.w;
  }
  __syncthreads();
  short* otile = vt + ofs;
#pragma unroll
  for (int i = 0; i < 2; ++i) {
    int c = t + i * NT;
    int d = c >> 3, k8 = (c & 7) * 8;
    s8v o;
#pragma unroll
    for (int u = 0; u < 8; ++u) o[u] = f2b(Vs[k8 + u][d]);
    *(s8v*)&otile[d * KT + k8] = o;
  }
}

// ---------------- attention: double-buffered async staging + bf16 MFMA ----------
__global__ __launch_bounds__(NT, 4) void attn_fast(
    const float* __restrict__ qg, const short* __restrict__ kr,
    const short* __restrict__ vt, float* __restrict__ og,
    const float* __restrict__ tab) {
  // unpadded, XOR-swizzled: phys chunk p of row r holds logical chunk p^(r&7)
  __shared__ __align__(16) short Ks[2][KT * DD];
  __shared__ __align__(16) short Vts[2][DD * KT];
  __shared__ __align__(16) short QP[QT * DD];  // Q tile; reused as per-wave P regions

  const int tid = threadIdx.x;
  const int lane = tid & 63;
  const int wv = tid >> 6;
  const int quad = lane >> 4;
  const int lx = lane & 15;
  const int xb = lx & 7;
  const int foff0 = ((quad ^ xb) << 3);
  const int foff1 = (((quad | 4) ^ xb) << 3);

  const int bid = blockIdx.x;
  const int qt = NKT - 1 - (bid >> 6);  // heavy q-tiles first
  const int bh = bid & 63;
  const int qbase = qt * QT;
  const float* Q = qg + (size_t)bh * SS * DD;
  float* O = og + (size_t)bh * SS * DD;
  const short* krh = kr + (size_t)bh * SS * DD;
  const short* vth = vt + (size_t)bh * NKT * (DD * KT);

  // ---- prologue: issue tile-0 DMA
#pragma unroll
  for (int i = 0; i < 2; ++i) {
    int c = wv * 128 + i * 64 + lane;
    int r = c >> 3, qp = c & 7;
    int qs = qp ^ (r & 7);
    gload16(krh + r * DD + qs * 8, &Ks[0][(wv * 128 + i * 64) * 8]);
    gload16(vth + r * DD + qs * 8, &Vts[0][(wv * 128 + i * 64) * 8]);
  }

  // ---- stage Q: rope * 0.125*log2e -> bf16 -> swizzled LDS
  const float qscale = 0.125f * LOG2E;
#pragma unroll
  for (int t = 0; t < 8; ++t) {
    int idx = tid + t * NT;
    int r = idx >> 5, j = idx & 31;
    float c, s;
    get_cs(tab, qbase + r, j, c, s);
    float x1 = Q[(size_t)(qbase + r) * DD + j];
    float x2 = Q[(size_t)(qbase + r) * DD + j + 32];
    int rb = r & 7;
    QP[r * DD + ((((j >> 3) ^ rb) << 3) | (j & 7))] = f2b((x1 * c - x2 * s) * qscale);
    QP[r * DD + (((((j >> 3) | 4) ^ rb) << 3) | (j & 7))] = f2b((x1 * s + x2 * c) * qscale);
  }
  __syncthreads();  // Q staged; tile-0 DMA drained (vmcnt)

  const int rq = wv * 16 + lx;
  s8v qf0 = *(const s8v*)&QP[rq * DD + foff0];
  s8v qf1 = *(const s8v*)&QP[rq * DD + foff1];

  // wave's P region == its Q-fragment rows (rows wv*16..wv*16+15): no cross-wave hazard
  short* Ps = &QP[wv * 16 * DD];

  float m_[4], l_[4];
  f4v o_[4];
#pragma unroll
  for (int r = 0; r < 4; ++r) { m_[r] = -INFINITY; l_[r] = 0.f; }
#pragma unroll
  for (int db = 0; db < 4; ++db) o_[db] = (f4v){0.f, 0.f, 0.f, 0.f};

  for (int kt = 0; kt <= qt; ++kt) {
    const int cur = kt & 1;
    if (kt) __syncthreads();  // prev-iter LDS reads done; tile-kt DMA (issued last iter) drained

    // ---- issue DMA for tile kt+1 into the other buffer (overlaps this iter's compute)
    if (kt < qt) {
      const short* ktile = krh + (size_t)(kt + 1) * (KT * DD);
      const short* vtile = vth + (size_t)(kt + 1) * (DD * KT);
      const int nxt = cur ^ 1;
#pragma unroll
      for (int i = 0; i < 2; ++i) {
        int c = wv * 128 + i * 64 + lane;
        int r = c >> 3, qp = c & 7;
        int qs = qp ^ (r & 7);
        gload16(ktile + r * DD + qs * 8, &Ks[nxt][(wv * 128 + i * 64) * 8]);
        gload16(vtile + r * DD + qs * 8, &Vts[nxt][(wv * 128 + i * 64) * 8]);
      }
    }

    // ---- scores S[16x64] per wave
    f4v sc[4];
#pragma unroll
    for (int nb = 0; nb < 4; ++nb) {
      const int rk = nb * 16 + lx;
      s8v kf0 = *(const s8v*)&Ks[cur][rk * DD + foff0];
      s8v kf1 = *(const s8v*)&Ks[cur][rk * DD + foff1];
      f4v z = (f4v){0.f, 0.f, 0.f, 0.f};
      z = __builtin_amdgcn_mfma_f32_16x16x32_bf16(qf0, kf0, z, 0, 0, 0);
      z = __builtin_amdgcn_mfma_f32_16x16x32_bf16(qf1, kf1, z, 0, 0, 0);
      sc[nb] = z;
    }

    if (kt == qt) {  // causal mask on diagonal tile
#pragma unroll
      for (int nb = 0; nb < 4; ++nb)
#pragma unroll
        for (int r = 0; r < 4; ++r)
          if (nb * 16 + lx > wv * 16 + quad * 4 + r) sc[nb][r] = -INFINITY;
    }

    // ---- online softmax (base-2); P bf16 -> wave's Ps region (swizzled)
#pragma unroll
    for (int r = 0; r < 4; ++r) {
      float mx = fmaxf(fmaxf(sc[0][r], sc[1][r]), fmaxf(sc[2][r], sc[3][r]));
      mx = fmaxf(mx, __shfl_xor(mx, 1, 16));
      mx = fmaxf(mx, __shfl_xor(mx, 2, 16));
      mx = fmaxf(mx, __shfl_xor(mx, 4, 16));
      mx = fmaxf(mx, __shfl_xor(mx, 8, 16));
      float mn = fmaxf(m_[r], mx);
      float al = __builtin_amdgcn_exp2f(m_[r] - mn);
      m_[r] = mn;
      float rs = 0.f;
      const int row = quad * 4 + r;
#pragma unroll
      for (int nb = 0; nb < 4; ++nb) {
        float p = __builtin_amdgcn_exp2f(sc[nb][r] - mn);
        rs += p;
        int pc = (nb * 2 + (lx >> 3)) ^ (row & 7);
        Ps[row * DD + pc * 8 + (lx & 7)] = f2b(p);
      }
      rs += __shfl_xor(rs, 1, 16);
      rs += __shfl_xor(rs, 2, 16);
      rs += __shfl_xor(rs, 4, 16);
      rs += __shfl_xor(rs, 8, 16);
      l_[r] = l_[r] * al + rs;
      o_[0][r] *= al; o_[1][r] *= al; o_[2][r] *= al; o_[3][r] *= al;
    }
    // no barrier: wave reads only its own Ps region; in-wave order via data dep

    // ---- PV
    s8v pf0 = *(const s8v*)&Ps[lx * DD + foff0];
    s8v pf1 = *(const s8v*)&Ps[lx * DD + foff1];
#pragma unroll
    for (int db = 0; db < 4; ++db) {
      const int rv = db * 16 + lx;
      s8v vf0 = *(const s8v*)&Vts[cur][rv * KT + foff0];
      s8v vf1 = *(const s8v*)&Vts[cur][rv * KT + foff1];
      o_[db] = __builtin_amdgcn_mfma_f32_16x16x32_bf16(pf0, vf0, o_[db], 0, 0, 0);
      o_[db] = __builtin_amdgcn_mfma_f32_16x16x32_bf16(pf1, vf1, o_[db], 0, 0, 0);
    }
  }

#pragma unroll
  for (int r = 0; r < 4; ++r) {
    float rinv = 1.0f / l_[r];
    int row = qbase + wv * 16 + quad * 4 + r;
#pragma unroll
    for (int db = 0; db < 4; ++db)
      O[(size_t)row * DD + db * 16 + lx] = o_[db][r] * rinv;
  }
}

// ---------------- fallback (round-2 proven path, used if ws too small) ----------
__global__ __launch_bounds__(NT, 4) void attn_fallback(
    const float* __restrict__ qg, const float* __restrict__ kg,
    const float* __restrict__ vg, float* __restrict__ og,
    const float* __restrict__ tab) {
  __shared__ __align__(16) short Qs[QT * LQ];
  __shared__ __align__(16) short Ks[KT * LQ];
  __shared__ __align__(16) short Vt[DD * LQ];
  __shared__ __align__(16) short Ps[4][16 * LQ];

  const int tid = threadIdx.x;
  const int lane = tid & 63;
  const int wv = tid >> 6;
  const int quad = lane >> 4;
  const int lx = lane & 15;

  const int bid = blockIdx.x;
  const int qt = NKT - 1 - (bid >> 6);
  const int bh = bid & 63;
  const int qbase = qt * QT;
  const size_t base = (size_t)bh * SS * DD;
  const float* Q = qg + base;
  const float* K = kg + base;
  const float* V = vg + base;
  float* O = og + base;

  const float qscale = 0.125f * LOG2E;
  for (int t = 0; t < 8; ++t) {
    int idx = tid + t * NT;
    int r = idx >> 5, j = idx & 31;
    float c, s;
    get_cs(tab, qbase + r, j, c, s);
    float x1 = Q[(size_t)(qbase + r) * DD + j];
    float x2 = Q[(size_t)(qbase + r) * DD + j + 32];
    Qs[r * LQ + j] = f2b((x1 * c - x2 * s) * qscale);
    Qs[r * LQ + j + 32] = f2b((x1 * s + x2 * c) * qscale);
  }
  __syncthreads();

  s8v qf0 = *(const s8v*)&Qs[(wv * 16 + lx) * LQ + quad * 8];
  s8v qf1 = *(const s8v*)&Qs[(wv * 16 + lx) * LQ + 32 + quad * 8];

  float m_[4], l_[4];
  f4v o_[4];
#pragma unroll
  for (int r = 0; r < 4; ++r) { m_[r] = -INFINITY; l_[r] = 0.f; }
#pragma unroll
  for (int db = 0; db < 4; ++db) o_[db] = (f4v){0.f, 0.f, 0.f, 0.f};

  for (int kt = 0; kt <= qt; ++kt) {
    const int kbase = kt * KT;
    __syncthreads();
    for (int t = 0; t < 8; ++t) {
      int idx = tid + t * NT;
      int r = idx >> 5, j = idx & 31;
      float c, s;
      get_cs(tab, kbase + r, j, c, s);
      float x1 = K[(size_t)(kbase + r) * DD + j];
      float x2 = K[(size_t)(kbase + r) * DD + j + 32];
      Ks[r * LQ + j] = f2b(x1 * c - x2 * s);
      Ks[r * LQ + j + 32] = f2b(x1 * s + x2 * c);
    }
    for (int t = 0; t < 4; ++t) {
      int i4 = tid + t * NT;
      int r = i4 >> 4, c4 = (i4 & 15) * 4;
      const float4 v = *(const float4*)&V[(size_t)(kbase + r) * DD + c4];
      Vt[(c4 + 0) * LQ + r] = f2b(v.x);
      Vt[(c4 + 1) * LQ + r] = f2b(v.y);
      Vt[(c4 + 2) * LQ + r] = f2b(v.z);
      Vt[(c4 + 3) * LQ + r] = f2b(v.w);
    }
    __syncthreads();

    f4v sc[4];
#pragma unroll
    for (int nb = 0; nb < 4; ++nb) {
      s8v kf0 = *(const s8v*)&Ks[(nb * 16 + lx) * LQ + quad * 8];
      s8v kf1 = *(const s8v*)&Ks[(nb * 16 + lx) * LQ + 32 + quad * 8];
      f4v z = (f4v){0.f, 0.f, 0.f, 0.f};
      z = __builtin_amdgcn_mfma_f32_16x16x32_bf16(qf0, kf0, z, 0, 0, 0);
      z = __builtin_amdgcn_mfma_f32_16x16x32_bf16(qf1, kf1, z, 0, 0, 0);
      sc[nb] = z;
    }
    if (kt == qt) {
#pragma unroll
      for (int nb = 0; nb < 4; ++nb)
#pragma unroll
        for (int r = 0; r < 4; ++r)
          if (kbase + nb * 16 + lx > qbase + wv * 16 + quad * 4 + r)
            sc[nb][r] = -INFINITY;
    }
#pragma unroll
    for (int r = 0; r < 4; ++r) {
      float mx = fmaxf(fmaxf(sc[0][r], sc[1][r]), fmaxf(sc[2][r], sc[3][r]));
      mx = fmaxf(mx, __shfl_xor(mx, 1, 16));
      mx = fmaxf(mx, __shfl_xor(mx, 2, 16));
      mx = fmaxf(mx, __shfl_xor(mx, 4, 16));
      mx = fmaxf(mx, __shfl_xor(mx, 8, 16));
      float mn = fmaxf(m_[r], mx);
      float al = __builtin_amdgcn_exp2f(m_[r] - mn);
      m_[r] = mn;
      float rs = 0.f;
#pragma unroll
      for (int nb = 0; nb < 4; ++nb) {
        float p = __builtin_amdgcn_exp2f(sc[nb][r] - mn);
        rs += p;
        Ps[wv][(quad * 4 + r) * LQ + nb * 16 + lx] = f2b(p);
      }
      rs += __shfl_xor(rs, 1, 16);
      rs += __shfl_xor(rs, 2, 16);
      rs += __shfl_xor(rs, 4, 16);
      rs += __shfl_xor(rs, 8, 16);
      l_[r] = l_[r] * al + rs;
      o_[0][r] *= al; o_[1][r] *= al; o_[2][r] *= al; o_[3][r] *= al;
    }
    s8v pf0 = *(const s8v*)&Ps[wv][lx * LQ + quad * 8];
    s8v pf1 = *(const s8v*)&Ps[wv][lx * LQ + 32 + quad * 8];
#pragma unroll
    for (int db = 0; db < 4; ++db) {
      s8v vf0 = *(const s8v*)&Vt[(db * 16 + lx) * LQ + quad * 8];
      s8v vf1 = *(const s8v*)&Vt[(db * 16 + lx) * LQ + 32 + quad * 8];
      o_[db] = __builtin_amdgcn_mfma_f32_16x16x32_bf16(pf0, vf0, o_[db], 0, 0, 0);
      o_[db] = __builtin_amdgcn_mfma_f32_16x16x32_bf16(pf1, vf1, o_[db], 0, 0, 0);
    }
  }
#pragma unroll
  for (int r = 0; r < 4; ++r) {
    float rinv = 1.0f / l_[r];
    int row = qbase + wv * 16 + quad * 4 + r;
#pragma unroll
    for (int db = 0; db < 4; ++db)
      O[(size_t)row * DD + db * 16 + lx] = o_[db][r] * rinv;
  }
}

extern "C" void kernel_launch(void* const* d_in, const int* in_sizes, int n_in,
                              void* d_out, int out_size, void* d_ws, size_t ws_size,
                              hipStream_t stream) {
  const float* q = (const float*)d_in[0];
  const float* k = (const float*)d_in[1];
  const float* v = (const float*)d_in[2];
  float* out = (float*)d_out;

  const size_t tab_bytes = (size_t)2 * SS * 32 * sizeof(float);  // 512 KB
  const size_t kr_bytes = (size_t)BH * SS * DD * sizeof(short);  // 16 MB
  const size_t vt_bytes = kr_bytes;                              // 16 MB
  const size_t need = tab_bytes + kr_bytes + vt_bytes;

  if (ws_size >= need) {
    float* tab = (float*)d_ws;
    short* kr = (short*)((char*)d_ws + tab_bytes);
    short* vt = (short*)((char*)d_ws + tab_bytes + kr_bytes);
    rope_tab_kernel<<<(SS * 32 + NT - 1) / NT, NT, 0, stream>>>(tab);
    prep_kv_kernel<<<BH * NKT, NT, 0, stream>>>(k, v, tab, kr, vt);
    attn_fast<<<dim3(BH * (SS / QT)), dim3(NT), 0, stream>>>(q, kr, vt, out, tab);
  } else {
    float* tab = nullptr;
    if (ws_size >= tab_bytes) {
      tab = (float*)d_ws;
      rope_tab_kernel<<<(SS * 32 + NT - 1) / NT, NT, 0, stream>>>(tab);
    }
    attn_fallback<<<dim3(BH * (SS / QT)), dim3(NT), 0, stream>>>(q, k, v, out, tab);
  }
}

// Round 5
// 237.762 us; speedup vs baseline: 3.2998x; 1.0294x over previous
//
#include <hip/hip_runtime.h>
#include <hip/hip_bf16.h>
#include <math.h>

#define SS 2048
#define DD 64
#define BH 64          // B*H
#define QT 128
#define KT 64
#define NT 256
#define NKT (SS / KT)  // 32
#define NQT (SS / QT)  // 16
#define LQ 72          // padded stride (shorts), fallback kernel only
#define LOG2E 1.4426950408889634f
#define IFS (13.287712379549449f / 32.0f)  // log2(10000)/32

typedef __attribute__((ext_vector_type(8))) short s8v;
typedef __attribute__((ext_vector_type(4))) float f4v;

__device__ __forceinline__ short f2b(float x) {
  __hip_bfloat16 h = __float2bfloat16(x);
  return *reinterpret_cast<short*>(&h);
}

// async global->LDS, 16B per lane; dest = wave-uniform base + lane*16
__device__ __forceinline__ void gload16(const void* g, void* l) {
  __builtin_amdgcn_global_load_lds(
      (const __attribute__((address_space(1))) void*)g,
      (__attribute__((address_space(3))) void*)l, 16, 0, 0);
}

// DPP cross-lane (VALU pipe, not LDS): quad_perm xor1=0xB1, xor2=0x4E, row_ror4=0x124, ror8=0x128
template <int CTRL>
__device__ __forceinline__ float dppf(float x) {
  int i = __builtin_bit_cast(int, x);
  i = __builtin_amdgcn_update_dpp(i, i, CTRL, 0xf, 0xf, false);
  return __builtin_bit_cast(float, i);
}
__device__ __forceinline__ float rowmax16(float x) {
  x = fmaxf(x, dppf<0xB1>(x));
  x = fmaxf(x, dppf<0x4E>(x));
  x = fmaxf(x, dppf<0x124>(x));
  x = fmaxf(x, dppf<0x128>(x));
  return x;
}
__device__ __forceinline__ float rowsum16(float x) {
  x += dppf<0xB1>(x);
  x += dppf<0x4E>(x);
  x += dppf<0x124>(x);
  x += dppf<0x128>(x);
  return x;
}

__device__ __forceinline__ void get_cs(const float* __restrict__ tab, int pos, int j,
                                       float& c, float& s) {
  if (tab) {
    c = tab[pos * 32 + j];
    s = tab[SS * 32 + pos * 32 + j];
  } else {
    float inv = exp2f(-(float)j * IFS);
    float ang = (float)pos * inv;
    sincosf(ang, &s, &c);
  }
}

// ---------------- fused prep: rope(K)->bf16 [h][s][d]; V^T bf16 tiles [h][kt][d][64]
__global__ __launch_bounds__(NT) void prep_kv_kernel(
    const float* __restrict__ kg, const float* __restrict__ vg,
    short* __restrict__ kr, short* __restrict__ vt) {
  __shared__ float Vs[KT][DD + 1];
  const int b = blockIdx.x;  // h*32 + kt
  const int kt = b & 31;
  const int t = threadIdx.x;
  const size_t ofs = (size_t)b * (KT * DD);
  const float* ktile = kg + ofs;
  short* krt = kr + ofs;

  // K: rope + bf16 (inline fp32 trig, same as reference's fp32 angles)
#pragma unroll
  for (int i = 0; i < 8; ++i) {
    int idx = t + i * NT;
    int r = idx >> 5, j = idx & 31;
    float inv = exp2f(-(float)j * IFS);
    float ang = (float)(kt * KT + r) * inv;
    float s, c;
    sincosf(ang, &s, &c);
    float x1 = ktile[r * DD + j], x2 = ktile[r * DD + j + 32];
    krt[r * DD + j] = f2b(x1 * c - x2 * s);
    krt[r * DD + j + 32] = f2b(x1 * s + x2 * c);
  }

  // V: transpose via LDS, bf16
  const float* vtile = vg + ofs;
#pragma unroll
  for (int i = 0; i < 4; ++i) {
    int s4 = t + i * NT;
    int r = s4 >> 4, c4 = (s4 & 15) * 4;
    float4 v = *(const float4*)&vtile[r * DD + c4];
    Vs[r][c4 + 0] = v.x;
    Vs[r][c4 + 1] = v.y;
    Vs[r][c4 + 2] = v.z;
    Vs[r][c4 + 3] = v.w;
  }
  __syncthreads();
  short* otile = vt + ofs;
#pragma unroll
  for (int i = 0; i < 2; ++i) {
    int c = t + i * NT;
    int d = c >> 3, k8 = (c & 7) * 8;
    s8v o;
#pragma unroll
    for (int u = 0; u < 8; ++u) o[u] = f2b(Vs[k8 + u][d]);
    *(s8v*)&otile[d * KT + k8] = o;
  }
}

// ---------------- attention: 128-row Q tiles, DPP softmax, dbuf async staging ----
__global__ __launch_bounds__(NT, 3) void attn_fast(
    const float* __restrict__ qg, const short* __restrict__ kr,
    const short* __restrict__ vt, float* __restrict__ og) {
  // unpadded, XOR-swizzled: phys chunk p of row r holds logical chunk p^(r&7)
  __shared__ __align__(16) short Ks[2][KT * DD];
  __shared__ __align__(16) short Vts[2][DD * KT];
  __shared__ __align__(16) short QP[QT * DD];  // Q tile; reused as per-wave P regions

  const int tid = threadIdx.x;
  const int lane = tid & 63;
  const int wv = tid >> 6;       // wave owns Q rows wv*32 .. wv*32+31 (2 units of 16)
  const int quad = lane >> 4;
  const int lx = lane & 15;
  const int xb = lx & 7;
  const int foff0 = ((quad ^ xb) << 3);
  const int foff1 = (((quad | 4) ^ xb) << 3);

  const int bid = blockIdx.x;
  const int qb = NQT - 1 - (bid >> 6);  // heavy q-tiles first
  const int bh = bid & 63;
  const int qbase = qb * QT;
  const int ktmax = 2 * qb + 1;
  const float* Q = qg + (size_t)bh * SS * DD;
  float* O = og + (size_t)bh * SS * DD;
  const short* krh = kr + (size_t)bh * SS * DD;
  const short* vth = vt + (size_t)bh * SS * DD;  // tiles are contiguous 4096-elt blocks

  // ---- prologue: issue tile-0 DMA (overlaps Q staging below)
#pragma unroll
  for (int i = 0; i < 2; ++i) {
    int c = wv * 128 + i * 64 + lane;
    int r = c >> 3, qp = c & 7;
    int qs = qp ^ (r & 7);
    gload16(krh + r * DD + qs * 8, &Ks[0][(wv * 128 + i * 64) * 8]);
    gload16(vth + r * DD + qs * 8, &Vts[0][(wv * 128 + i * 64) * 8]);
  }

  // ---- stage Q: inline rope * 0.125*log2e -> bf16 -> swizzled LDS
  const float qscale = 0.125f * LOG2E;
#pragma unroll
  for (int t = 0; t < 16; ++t) {
    int idx = tid + t * NT;  // 4096 (row, j) pairs: 128 rows x 32
    int r = idx >> 5, j = idx & 31;
    float inv = exp2f(-(float)j * IFS);
    float ang = (float)(qbase + r) * inv;
    float s, c;
    sincosf(ang, &s, &c);
    float x1 = Q[(size_t)(qbase + r) * DD + j];
    float x2 = Q[(size_t)(qbase + r) * DD + j + 32];
    int rb = r & 7;
    QP[r * DD + ((((j >> 3) ^ rb) << 3) | (j & 7))] = f2b((x1 * c - x2 * s) * qscale);
    QP[r * DD + (((((j >> 3) | 4) ^ rb) << 3) | (j & 7))] = f2b((x1 * s + x2 * c) * qscale);
  }
  __syncthreads();  // Q staged; tile-0 DMA drained

  const int rq0 = wv * 32 + lx;  // (wv*32+lx)&7 == lx&7 == xb; +16 preserves &7
  s8v qf00 = *(const s8v*)&QP[rq0 * DD + foff0];
  s8v qf01 = *(const s8v*)&QP[rq0 * DD + foff1];
  s8v qf10 = *(const s8v*)&QP[(rq0 + 16) * DD + foff0];
  s8v qf11 = *(const s8v*)&QP[(rq0 + 16) * DD + foff1];

  // wave's P region == its own Q rows: no cross-wave hazard, in-wave order via lgkmcnt
  short* Ps = &QP[wv * 32 * DD];

  float m_[2][4], l_[2][4];
  f4v o_[2][4];
#pragma unroll
  for (int u = 0; u < 2; ++u)
#pragma unroll
    for (int r = 0; r < 4; ++r) {
      m_[u][r] = -INFINITY;
      l_[u][r] = 0.f;
      o_[u][r] = (f4v){0.f, 0.f, 0.f, 0.f};  // placeholder; real acc below
    }
#pragma unroll
  for (int u = 0; u < 2; ++u)
#pragma unroll
    for (int db = 0; db < 4; ++db) o_[u][db] = (f4v){0.f, 0.f, 0.f, 0.f};

  for (int kt = 0; kt <= ktmax; ++kt) {
    const int cur = kt & 1;
    if (kt) __syncthreads();  // prev-iter LDS reads done; tile-kt DMA drained

    // ---- issue DMA for tile kt+1 (overlaps this iter's compute)
    if (kt < ktmax) {
      const short* ktile = krh + (size_t)(kt + 1) * (KT * DD);
      const short* vtile = vth + (size_t)(kt + 1) * (DD * KT);
      const int nxt = cur ^ 1;
#pragma unroll
      for (int i = 0; i < 2; ++i) {
        int c = wv * 128 + i * 64 + lane;
        int r = c >> 3, qp = c & 7;
        int qs = qp ^ (r & 7);
        gload16(ktile + r * DD + qs * 8, &Ks[nxt][(wv * 128 + i * 64) * 8]);
        gload16(vtile + r * DD + qs * 8, &Vts[nxt][(wv * 128 + i * 64) * 8]);
      }
    }

    const int kbase = kt * KT;
    if (kbase <= qbase + wv * 32 + 31) {  // wave-uniform skip of fully-masked tiles
      // ---- scores: two 16x64 S tiles per wave; K frags shared across units
      f4v sc[2][4];
#pragma unroll
      for (int nb = 0; nb < 4; ++nb) {
        const int rk = nb * 16 + lx;
        s8v kf0 = *(const s8v*)&Ks[cur][rk * DD + foff0];
        s8v kf1 = *(const s8v*)&Ks[cur][rk * DD + foff1];
        f4v z0 = (f4v){0.f, 0.f, 0.f, 0.f};
        z0 = __builtin_amdgcn_mfma_f32_16x16x32_bf16(qf00, kf0, z0, 0, 0, 0);
        z0 = __builtin_amdgcn_mfma_f32_16x16x32_bf16(qf01, kf1, z0, 0, 0, 0);
        sc[0][nb] = z0;
        f4v z1 = (f4v){0.f, 0.f, 0.f, 0.f};
        z1 = __builtin_amdgcn_mfma_f32_16x16x32_bf16(qf10, kf0, z1, 0, 0, 0);
        z1 = __builtin_amdgcn_mfma_f32_16x16x32_bf16(qf11, kf1, z1, 0, 0, 0);
        sc[1][nb] = z1;
      }

#pragma unroll
      for (int u = 0; u < 2; ++u) {
        const int rowbase = qbase + wv * 32 + u * 16;
        if (kbase + 63 > rowbase) {  // diagonal-region mask
#pragma unroll
          for (int nb = 0; nb < 4; ++nb)
#pragma unroll
            for (int r = 0; r < 4; ++r)
              if (kbase + nb * 16 + lx > rowbase + quad * 4 + r)
                sc[u][nb][r] = -INFINITY;
        }

        // ---- online softmax (base-2), DPP reductions; P bf16 -> wave's Ps
#pragma unroll
        for (int r = 0; r < 4; ++r) {
          float mx = fmaxf(fmaxf(sc[u][0][r], sc[u][1][r]),
                           fmaxf(sc[u][2][r], sc[u][3][r]));
          mx = rowmax16(mx);
          float mn = fmaxf(m_[u][r], mx);
          float al = __builtin_amdgcn_exp2f(m_[u][r] - mn);
          m_[u][r] = mn;
          float rs = 0.f;
          const int rl = quad * 4 + r;           // row within unit (0..15)
          const int row_l = u * 16 + rl;         // row within wave's P region
#pragma unroll
          for (int nb = 0; nb < 4; ++nb) {
            float p = __builtin_amdgcn_exp2f(sc[u][nb][r] - mn);
            rs += p;
            int pc = (nb * 2 + (lx >> 3)) ^ (rl & 7);
            Ps[row_l * DD + pc * 8 + (lx & 7)] = f2b(p);
          }
          rs = rowsum16(rs);
          l_[u][r] = l_[u][r] * al + rs;
          o_[u][0][r] *= al; o_[u][1][r] *= al;
          o_[u][2][r] *= al; o_[u][3][r] *= al;
        }
      }

      // ---- PV: V frags shared across units
      s8v pf00 = *(const s8v*)&Ps[lx * DD + foff0];
      s8v pf01 = *(const s8v*)&Ps[lx * DD + foff1];
      s8v pf10 = *(const s8v*)&Ps[(16 + lx) * DD + foff0];
      s8v pf11 = *(const s8v*)&Ps[(16 + lx) * DD + foff1];
#pragma unroll
      for (int db = 0; db < 4; ++db) {
        const int rv = db * 16 + lx;
        s8v vf0 = *(const s8v*)&Vts[cur][rv * KT + foff0];
        s8v vf1 = *(const s8v*)&Vts[cur][rv * KT + foff1];
        o_[0][db] = __builtin_amdgcn_mfma_f32_16x16x32_bf16(pf00, vf0, o_[0][db], 0, 0, 0);
        o_[0][db] = __builtin_amdgcn_mfma_f32_16x16x32_bf16(pf01, vf1, o_[0][db], 0, 0, 0);
        o_[1][db] = __builtin_amdgcn_mfma_f32_16x16x32_bf16(pf10, vf0, o_[1][db], 0, 0, 0);
        o_[1][db] = __builtin_amdgcn_mfma_f32_16x16x32_bf16(pf11, vf1, o_[1][db], 0, 0, 0);
      }
    }
  }

  // ---- epilogue: normalize, store fp32
#pragma unroll
  for (int u = 0; u < 2; ++u)
#pragma unroll
    for (int r = 0; r < 4; ++r) {
      float rinv = 1.0f / l_[u][r];
      int row = qbase + wv * 32 + u * 16 + quad * 4 + r;
#pragma unroll
      for (int db = 0; db < 4; ++db)
        O[(size_t)row * DD + db * 16 + lx] = o_[u][db][r] * rinv;
    }
}

// ---------------- fallback (round-4 proven path, used if ws too small) ----------
__global__ __launch_bounds__(NT, 4) void attn_fallback(
    const float* __restrict__ qg, const float* __restrict__ kg,
    const float* __restrict__ vg, float* __restrict__ og,
    const float* __restrict__ tab) {
  __shared__ __align__(16) short Qs[64 * LQ];
  __shared__ __align__(16) short Ksh[64 * LQ];
  __shared__ __align__(16) short Vt[DD * LQ];
  __shared__ __align__(16) short Ps[4][16 * LQ];

  const int tid = threadIdx.x;
  const int lane = tid & 63;
  const int wv = tid >> 6;
  const int quad = lane >> 4;
  const int lx = lane & 15;

  const int bid = blockIdx.x;
  const int qt = NKT - 1 - (bid >> 6);
  const int bh = bid & 63;
  const int qbase = qt * 64;
  const size_t base = (size_t)bh * SS * DD;
  const float* Q = qg + base;
  const float* K = kg + base;
  const float* V = vg + base;
  float* O = og + base;

  const float qscale = 0.125f * LOG2E;
  for (int t = 0; t < 8; ++t) {
    int idx = tid + t * NT;
    int r = idx >> 5, j = idx & 31;
    float c, s;
    get_cs(tab, qbase + r, j, c, s);
    float x1 = Q[(size_t)(qbase + r) * DD + j];
    float x2 = Q[(size_t)(qbase + r) * DD + j + 32];
    Qs[r * LQ + j] = f2b((x1 * c - x2 * s) * qscale);
    Qs[r * LQ + j + 32] = f2b((x1 * s + x2 * c) * qscale);
  }
  __syncthreads();

  s8v qf0 = *(const s8v*)&Qs[(wv * 16 + lx) * LQ + quad * 8];
  s8v qf1 = *(const s8v*)&Qs[(wv * 16 + lx) * LQ + 32 + quad * 8];

  float m_[4], l_[4];
  f4v o_[4];
#pragma unroll
  for (int r = 0; r < 4; ++r) { m_[r] = -INFINITY; l_[r] = 0.f; }
#pragma unroll
  for (int db = 0; db < 4; ++db) o_[db] = (f4v){0.f, 0.f, 0.f, 0.f};

  for (int kt = 0; kt <= qt; ++kt) {
    const int kbase = kt * 64;
    __syncthreads();
    for (int t = 0; t < 8; ++t) {
      int idx = tid + t * NT;
      int r = idx >> 5, j = idx & 31;
      float c, s;
      get_cs(tab, kbase + r, j, c, s);
      float x1 = K[(size_t)(kbase + r) * DD + j];
      float x2 = K[(size_t)(kbase + r) * DD + j + 32];
      Ksh[r * LQ + j] = f2b(x1 * c - x2 * s);
      Ksh[r * LQ + j + 32] = f2b(x1 * s + x2 * c);
    }
    for (int t = 0; t < 4; ++t) {
      int i4 = tid + t * NT;
      int r = i4 >> 4, c4 = (i4 & 15) * 4;
      const float4 v = *(const float4*)&V[(size_t)(kbase + r) * DD + c4];
      Vt[(c4 + 0) * LQ + r] = f2b(v.x);
      Vt[(c4 + 1) * LQ + r] = f2b(v.y);
      Vt[(c4 + 2) * LQ + r] = f2b(v.z);
      Vt[(c4 + 3) * LQ + r] = f2b(v.w);
    }
    __syncthreads();

    f4v sc[4];
#pragma unroll
    for (int nb = 0; nb < 4; ++nb) {
      s8v kf0 = *(const s8v*)&Ksh[(nb * 16 + lx) * LQ + quad * 8];
      s8v kf1 = *(const s8v*)&Ksh[(nb * 16 + lx) * LQ + 32 + quad * 8];
      f4v z = (f4v){0.f, 0.f, 0.f, 0.f};
      z = __builtin_amdgcn_mfma_f32_16x16x32_bf16(qf0, kf0, z, 0, 0, 0);
      z = __builtin_amdgcn_mfma_f32_16x16x32_bf16(qf1, kf1, z, 0, 0, 0);
      sc[nb] = z;
    }
    if (kt == qt) {
#pragma unroll
      for (int nb = 0; nb < 4; ++nb)
#pragma unroll
        for (int r = 0; r < 4; ++r)
          if (kbase + nb * 16 + lx > qbase + wv * 16 + quad * 4 + r)
            sc[nb][r] = -INFINITY;
    }
#pragma unroll
    for (int r = 0; r < 4; ++r) {
      float mx = fmaxf(fmaxf(sc[0][r], sc[1][r]), fmaxf(sc[2][r], sc[3][r]));
      mx = rowmax16(mx);
      float mn = fmaxf(m_[r], mx);
      float al = __builtin_amdgcn_exp2f(m_[r] - mn);
      m_[r] = mn;
      float rs = 0.f;
#pragma unroll
      for (int nb = 0; nb < 4; ++nb) {
        float p = __builtin_amdgcn_exp2f(sc[nb][r] - mn);
        rs += p;
        Ps[wv][(quad * 4 + r) * LQ + nb * 16 + lx] = f2b(p);
      }
      rs = rowsum16(rs);
      l_[r] = l_[r] * al + rs;
      o_[0][r] *= al; o_[1][r] *= al; o_[2][r] *= al; o_[3][r] *= al;
    }
    s8v pf0 = *(const s8v*)&Ps[wv][lx * LQ + quad * 8];
    s8v pf1 = *(const s8v*)&Ps[wv][lx * LQ + 32 + quad * 8];
#pragma unroll
    for (int db = 0; db < 4; ++db) {
      s8v vf0 = *(const s8v*)&Vt[(db * 16 + lx) * LQ + quad * 8];
      s8v vf1 = *(const s8v*)&Vt[(db * 16 + lx) * LQ + 32 + quad * 8];
      o_[db] = __builtin_amdgcn_mfma_f32_16x16x32_bf16(pf0, vf0, o_[db], 0, 0, 0);
      o_[db] = __builtin_amdgcn_mfma_f32_16x16x32_bf16(pf1, vf1, o_[db], 0, 0, 0);
    }
  }
#pragma unroll
  for (int r = 0; r < 4; ++r) {
    float rinv = 1.0f / l_[r];
    int row = qbase + wv * 16 + quad * 4 + r;
#pragma unroll
    for (int db = 0; db < 4; ++db)
      O[(size_t)row * DD + db * 16 + lx] = o_[db][r] * rinv;
  }
}

extern "C" void kernel_launch(void* const* d_in, const int* in_sizes, int n_in,
                              void* d_out, int out_size, void* d_ws, size_t ws_size,
                              hipStream_t stream) {
  const float* q = (const float*)d_in[0];
  const float* k = (const float*)d_in[1];
  const float* v = (const float*)d_in[2];
  float* out = (float*)d_out;

  const size_t kr_bytes = (size_t)BH * SS * DD * sizeof(short);  // 16 MB
  const size_t vt_bytes = kr_bytes;                              // 16 MB
  const size_t need = kr_bytes + vt_bytes;                       // 32 MB

  if (ws_size >= need) {
    short* kr = (short*)d_ws;
    short* vt = (short*)((char*)d_ws + kr_bytes);
    prep_kv_kernel<<<BH * NKT, NT, 0, stream>>>(k, v, kr, vt);
    attn_fast<<<dim3(BH * NQT), dim3(NT), 0, stream>>>(q, kr, vt, out);
  } else {
    attn_fallback<<<dim3(BH * NKT), dim3(NT), 0, stream>>>(q, k, v, out, nullptr);
  }
}

// Round 6
// 213.630 us; speedup vs baseline: 3.6726x; 1.1130x over previous
//
#include <hip/hip_runtime.h>
#include <hip/hip_bf16.h>
#include <math.h>

#define SS 2048
#define DD 64
#define BH 64          // B*H
#define QT 64
#define KT 64
#define NT 256
#define NKT (SS / KT)  // 32
#define LQ 72          // padded stride (shorts), fallback kernel only
#define LOG2E 1.4426950408889634f
#define IFS (13.287712379549449f / 32.0f)  // log2(10000)/32

typedef __attribute__((ext_vector_type(8))) short s8v;
typedef __attribute__((ext_vector_type(4))) short s4v;
typedef __attribute__((ext_vector_type(4))) float f4v;

__device__ __forceinline__ short f2b(float x) {
  __hip_bfloat16 h = __float2bfloat16(x);
  return *reinterpret_cast<short*>(&h);
}

// async global->LDS, 16B per lane; dest = wave-uniform base + lane*16
__device__ __forceinline__ void gload16(const void* g, void* l) {
  __builtin_amdgcn_global_load_lds(
      (const __attribute__((address_space(1))) void*)g,
      (__attribute__((address_space(3))) void*)l, 16, 0, 0);
}

// DPP cross-lane (VALU pipe, not LDS): quad_perm xor1=0xB1, xor2=0x4E, row_ror4=0x124, ror8=0x128
template <int CTRL>
__device__ __forceinline__ float dppf(float x) {
  int i = __builtin_bit_cast(int, x);
  i = __builtin_amdgcn_update_dpp(i, i, CTRL, 0xf, 0xf, false);
  return __builtin_bit_cast(float, i);
}
__device__ __forceinline__ float rowmax16(float x) {
  x = fmaxf(x, dppf<0xB1>(x));
  x = fmaxf(x, dppf<0x4E>(x));
  x = fmaxf(x, dppf<0x124>(x));
  x = fmaxf(x, dppf<0x128>(x));
  return x;
}
__device__ __forceinline__ float rowsum16(float x) {
  x += dppf<0xB1>(x);
  x += dppf<0x4E>(x);
  x += dppf<0x124>(x);
  x += dppf<0x128>(x);
  return x;
}

__device__ __forceinline__ void rope_cs(int pos, int j, float& c, float& s) {
  float inv = exp2f(-(float)j * IFS);
  float ang = (float)pos * inv;
  __sincosf(ang, &s, &c);  // fast trig: angle err ~1e-4 rad << bf16 rounding
}

// ---------------- fused prep: rope(K)->bf16 [h][s][d]; permuted V^T bf16 tiles ----
// V' tile layout: otile[d*64 + k'] = V[sigma(k')][d], sigma(k') = (k'&3)*16 + (k'>>2)
// (column order matches P-write permutation k' = lx*4 + nb in attn)
__global__ __launch_bounds__(NT) void prep_kv_kernel(
    const float* __restrict__ kg, const float* __restrict__ vg,
    short* __restrict__ kr, short* __restrict__ vt) {
  __shared__ float Vs[KT][DD + 1];
  const int b = blockIdx.x;  // h*32 + kt
  const int kt = b & 31;
  const int t = threadIdx.x;
  const size_t ofs = (size_t)b * (KT * DD);
  const float* ktile = kg + ofs;
  short* krt = kr + ofs;

  // K: rope + bf16
#pragma unroll
  for (int i = 0; i < 8; ++i) {
    int idx = t + i * NT;
    int r = idx >> 5, j = idx & 31;
    float s, c;
    rope_cs(kt * KT + r, j, c, s);
    float x1 = ktile[r * DD + j], x2 = ktile[r * DD + j + 32];
    krt[r * DD + j] = f2b(x1 * c - x2 * s);
    krt[r * DD + j + 32] = f2b(x1 * s + x2 * c);
  }

  // V: transpose via LDS, bf16, permuted row order
  const float* vtile = vg + ofs;
#pragma unroll
  for (int i = 0; i < 4; ++i) {
    int s4 = t + i * NT;
    int r = s4 >> 4, c4 = (s4 & 15) * 4;
    float4 v = *(const float4*)&vtile[r * DD + c4];
    Vs[r][c4 + 0] = v.x;
    Vs[r][c4 + 1] = v.y;
    Vs[r][c4 + 2] = v.z;
    Vs[r][c4 + 3] = v.w;
  }
  __syncthreads();
  short* otile = vt + ofs;
#pragma unroll
  for (int i = 0; i < 2; ++i) {
    int c = t + i * NT;
    int d = c >> 3, k8 = (c & 7) * 8;
    s8v o;
#pragma unroll
    for (int u = 0; u < 8; ++u) {
      int kp = k8 + u;
      int src = ((kp & 3) << 4) + (kp >> 2);  // sigma(k')
      o[u] = f2b(Vs[src][d]);
    }
    *(s8v*)&otile[d * KT + k8] = o;
  }
}

// ---------------- attention: QT=64, dbuf async staging, DPP softmax, packed P ----
__global__ __launch_bounds__(NT, 4) void attn_fast(
    const float* __restrict__ qg, const short* __restrict__ kr,
    const short* __restrict__ vt, float* __restrict__ og) {
  // unpadded, XOR-swizzled: phys chunk p of row r holds logical chunk p^(r&7)
  __shared__ __align__(16) short Ks[2][KT * DD];
  __shared__ __align__(16) short Vts[2][DD * KT];
  __shared__ __align__(16) short QP[QT * DD];  // Q tile; reused as per-wave P regions

  const int tid = threadIdx.x;
  const int lane = tid & 63;
  const int wv = tid >> 6;     // wave owns Q rows wv*16..wv*16+15
  const int quad = lane >> 4;
  const int lx = lane & 15;
  const int xb = lx & 7;
  const int foff0 = ((quad ^ xb) << 3);
  const int foff1 = (((quad | 4) ^ xb) << 3);

  const int bid = blockIdx.x;
  const int qt = NKT - 1 - (bid >> 6);  // heavy q-tiles first
  const int bh = bid & 63;
  const int qbase = qt * QT;
  const float* Q = qg + (size_t)bh * SS * DD;
  float* O = og + (size_t)bh * SS * DD;
  const short* krh = kr + (size_t)bh * SS * DD;
  const short* vth = vt + (size_t)bh * SS * DD;  // permuted V^T, contiguous 4096-elt tiles

  // ---- prologue: issue tile-0 DMA (overlaps Q staging)
#pragma unroll
  for (int i = 0; i < 2; ++i) {
    int c = wv * 128 + i * 64 + lane;
    int r = c >> 3, qp = c & 7;
    int qs = qp ^ (r & 7);
    gload16(krh + r * DD + qs * 8, &Ks[0][(wv * 128 + i * 64) * 8]);
    gload16(vth + r * DD + qs * 8, &Vts[0][(wv * 128 + i * 64) * 8]);
  }

  // ---- stage Q: rope * 0.125*log2e -> bf16 -> swizzled LDS
  const float qscale = 0.125f * LOG2E;
#pragma unroll
  for (int t = 0; t < 8; ++t) {
    int idx = tid + t * NT;  // 2048 (row, j) pairs: 64 rows x 32
    int r = idx >> 5, j = idx & 31;
    float s, c;
    rope_cs(qbase + r, j, c, s);
    float x1 = Q[(size_t)(qbase + r) * DD + j];
    float x2 = Q[(size_t)(qbase + r) * DD + j + 32];
    int rb = r & 7;
    QP[r * DD + ((((j >> 3) ^ rb) << 3) | (j & 7))] = f2b((x1 * c - x2 * s) * qscale);
    QP[r * DD + (((((j >> 3) | 4) ^ rb) << 3) | (j & 7))] = f2b((x1 * s + x2 * c) * qscale);
  }
  __syncthreads();  // Q staged; tile-0 DMA drained

  const int rq = wv * 16 + lx;  // (wv*16+lx)&7 == lx&7 == xb
  s8v qf0 = *(const s8v*)&QP[rq * DD + foff0];
  s8v qf1 = *(const s8v*)&QP[rq * DD + foff1];

  // wave's P region == its own Q rows: no cross-wave hazard; in-wave order via lgkmcnt
  short* Ps = &QP[wv * 16 * DD];

  float m_[4], l_[4];
  f4v o_[4];
#pragma unroll
  for (int r = 0; r < 4; ++r) { m_[r] = -INFINITY; l_[r] = 0.f; }
#pragma unroll
  for (int db = 0; db < 4; ++db) o_[db] = (f4v){0.f, 0.f, 0.f, 0.f};

  for (int kt = 0; kt <= qt; ++kt) {
    const int cur = kt & 1;
    if (kt) __syncthreads();  // prev-iter LDS reads done; tile-kt DMA drained

    // ---- issue DMA for tile kt+1 (overlaps this iter's compute)
    if (kt < qt) {
      const short* ktile = krh + (size_t)(kt + 1) * (KT * DD);
      const short* vtile = vth + (size_t)(kt + 1) * (DD * KT);
      const int nxt = cur ^ 1;
#pragma unroll
      for (int i = 0; i < 2; ++i) {
        int c = wv * 128 + i * 64 + lane;
        int r = c >> 3, qp = c & 7;
        int qs = qp ^ (r & 7);
        gload16(ktile + r * DD + qs * 8, &Ks[nxt][(wv * 128 + i * 64) * 8]);
        gload16(vtile + r * DD + qs * 8, &Vts[nxt][(wv * 128 + i * 64) * 8]);
      }
    }

    // ---- scores S[16x64] per wave
    f4v sc[4];
#pragma unroll
    for (int nb = 0; nb < 4; ++nb) {
      const int rk = nb * 16 + lx;
      s8v kf0 = *(const s8v*)&Ks[cur][rk * DD + foff0];
      s8v kf1 = *(const s8v*)&Ks[cur][rk * DD + foff1];
      f4v z = (f4v){0.f, 0.f, 0.f, 0.f};
      z = __builtin_amdgcn_mfma_f32_16x16x32_bf16(qf0, kf0, z, 0, 0, 0);
      z = __builtin_amdgcn_mfma_f32_16x16x32_bf16(qf1, kf1, z, 0, 0, 0);
      sc[nb] = z;
    }

    if (kt == qt) {  // causal mask on diagonal tile (cols are original k order)
#pragma unroll
      for (int nb = 0; nb < 4; ++nb)
#pragma unroll
        for (int r = 0; r < 4; ++r)
          if (nb * 16 + lx > wv * 16 + quad * 4 + r) sc[nb][r] = -INFINITY;
    }

    // ---- online softmax (base-2), DPP reductions; packed P write (permuted cols)
#pragma unroll
    for (int r = 0; r < 4; ++r) {
      float mx = fmaxf(fmaxf(sc[0][r], sc[1][r]), fmaxf(sc[2][r], sc[3][r]));
      mx = rowmax16(mx);
      float mn = fmaxf(m_[r], mx);
      float al = __builtin_amdgcn_exp2f(m_[r] - mn);
      m_[r] = mn;
      const int rl = quad * 4 + r;
      float p0 = __builtin_amdgcn_exp2f(sc[0][r] - mn);
      float p1 = __builtin_amdgcn_exp2f(sc[1][r] - mn);
      float p2 = __builtin_amdgcn_exp2f(sc[2][r] - mn);
      float p3 = __builtin_amdgcn_exp2f(sc[3][r] - mn);
      float rs = rowsum16((p0 + p1) + (p2 + p3));
      // k' = lx*4 + nb: lane's 4 values contiguous -> one b64 store (swizzled)
      s4v pk = {f2b(p0), f2b(p1), f2b(p2), f2b(p3)};
      *(s4v*)&Ps[rl * DD + (((lx >> 1) ^ (rl & 7)) << 3) + ((lx & 1) << 2)] = pk;
      l_[r] = l_[r] * al + rs;
      o_[0][r] *= al; o_[1][r] *= al; o_[2][r] *= al; o_[3][r] *= al;
    }
    // no barrier: wave reads only its own Ps region

    // ---- PV (V' rows are sigma-permuted to match P' columns)
    s8v pf0 = *(const s8v*)&Ps[lx * DD + foff0];
    s8v pf1 = *(const s8v*)&Ps[lx * DD + foff1];
#pragma unroll
    for (int db = 0; db < 4; ++db) {
      const int rv = db * 16 + lx;
      s8v vf0 = *(const s8v*)&Vts[cur][rv * KT + foff0];
      s8v vf1 = *(const s8v*)&Vts[cur][rv * KT + foff1];
      o_[db] = __builtin_amdgcn_mfma_f32_16x16x32_bf16(pf0, vf0, o_[db], 0, 0, 0);
      o_[db] = __builtin_amdgcn_mfma_f32_16x16x32_bf16(pf1, vf1, o_[db], 0, 0, 0);
    }
  }

  // ---- epilogue: normalize, store fp32
#pragma unroll
  for (int r = 0; r < 4; ++r) {
    float rinv = 1.0f / l_[r];
    int row = qbase + wv * 16 + quad * 4 + r;
#pragma unroll
    for (int db = 0; db < 4; ++db)
      O[(size_t)row * DD + db * 16 + lx] = o_[db][r] * rinv;
  }
}

// ---------------- fallback (proven path, used only if ws too small) ----------
__global__ __launch_bounds__(NT, 4) void attn_fallback(
    const float* __restrict__ qg, const float* __restrict__ kg,
    const float* __restrict__ vg, float* __restrict__ og) {
  __shared__ __align__(16) short Qs[64 * LQ];
  __shared__ __align__(16) short Ksh[64 * LQ];
  __shared__ __align__(16) short Vt[DD * LQ];
  __shared__ __align__(16) short Ps[4][16 * LQ];

  const int tid = threadIdx.x;
  const int lane = tid & 63;
  const int wv = tid >> 6;
  const int quad = lane >> 4;
  const int lx = lane & 15;

  const int bid = blockIdx.x;
  const int qt = NKT - 1 - (bid >> 6);
  const int bh = bid & 63;
  const int qbase = qt * 64;
  const size_t base = (size_t)bh * SS * DD;
  const float* Q = qg + base;
  const float* K = kg + base;
  const float* V = vg + base;
  float* O = og + base;

  const float qscale = 0.125f * LOG2E;
  for (int t = 0; t < 8; ++t) {
    int idx = tid + t * NT;
    int r = idx >> 5, j = idx & 31;
    float c, s;
    rope_cs(qbase + r, j, c, s);
    float x1 = Q[(size_t)(qbase + r) * DD + j];
    float x2 = Q[(size_t)(qbase + r) * DD + j + 32];
    Qs[r * LQ + j] = f2b((x1 * c - x2 * s) * qscale);
    Qs[r * LQ + j + 32] = f2b((x1 * s + x2 * c) * qscale);
  }
  __syncthreads();

  s8v qf0 = *(const s8v*)&Qs[(wv * 16 + lx) * LQ + quad * 8];
  s8v qf1 = *(const s8v*)&Qs[(wv * 16 + lx) * LQ + 32 + quad * 8];

  float m_[4], l_[4];
  f4v o_[4];
#pragma unroll
  for (int r = 0; r < 4; ++r) { m_[r] = -INFINITY; l_[r] = 0.f; }
#pragma unroll
  for (int db = 0; db < 4; ++db) o_[db] = (f4v){0.f, 0.f, 0.f, 0.f};

  for (int kt = 0; kt <= qt; ++kt) {
    const int kbase = kt * 64;
    __syncthreads();
    for (int t = 0; t < 8; ++t) {
      int idx = tid + t * NT;
      int r = idx >> 5, j = idx & 31;
      float c, s;
      rope_cs(kbase + r, j, c, s);
      float x1 = K[(size_t)(kbase + r) * DD + j];
      float x2 = K[(size_t)(kbase + r) * DD + j + 32];
      Ksh[r * LQ + j] = f2b(x1 * c - x2 * s);
      Ksh[r * LQ + j + 32] = f2b(x1 * s + x2 * c);
    }
    for (int t = 0; t < 4; ++t) {
      int i4 = tid + t * NT;
      int r = i4 >> 4, c4 = (i4 & 15) * 4;
      const float4 v = *(const float4*)&V[(size_t)(kbase + r) * DD + c4];
      Vt[(c4 + 0) * LQ + r] = f2b(v.x);
      Vt[(c4 + 1) * LQ + r] = f2b(v.y);
      Vt[(c4 + 2) * LQ + r] = f2b(v.z);
      Vt[(c4 + 3) * LQ + r] = f2b(v.w);
    }
    __syncthreads();

    f4v sc[4];
#pragma unroll
    for (int nb = 0; nb < 4; ++nb) {
      s8v kf0 = *(const s8v*)&Ksh[(nb * 16 + lx) * LQ + quad * 8];
      s8v kf1 = *(const s8v*)&Ksh[(nb * 16 + lx) * LQ + 32 + quad * 8];
      f4v z = (f4v){0.f, 0.f, 0.f, 0.f};
      z = __builtin_amdgcn_mfma_f32_16x16x32_bf16(qf0, kf0, z, 0, 0, 0);
      z = __builtin_amdgcn_mfma_f32_16x16x32_bf16(qf1, kf1, z, 0, 0, 0);
      sc[nb] = z;
    }
    if (kt == qt) {
#pragma unroll
      for (int nb = 0; nb < 4; ++nb)
#pragma unroll
        for (int r = 0; r < 4; ++r)
          if (kbase + nb * 16 + lx > qbase + wv * 16 + quad * 4 + r)
            sc[nb][r] = -INFINITY;
    }
#pragma unroll
    for (int r = 0; r < 4; ++r) {
      float mx = fmaxf(fmaxf(sc[0][r], sc[1][r]), fmaxf(sc[2][r], sc[3][r]));
      mx = rowmax16(mx);
      float mn = fmaxf(m_[r], mx);
      float al = __builtin_amdgcn_exp2f(m_[r] - mn);
      m_[r] = mn;
      float rs = 0.f;
#pragma unroll
      for (int nb = 0; nb < 4; ++nb) {
        float p = __builtin_amdgcn_exp2f(sc[nb][r] - mn);
        rs += p;
        Ps[wv][(quad * 4 + r) * LQ + nb * 16 + lx] = f2b(p);
      }
      rs = rowsum16(rs);
      l_[r] = l_[r] * al + rs;
      o_[0][r] *= al; o_[1][r] *= al; o_[2][r] *= al; o_[3][r] *= al;
    }
    s8v pf0 = *(const s8v*)&Ps[wv][lx * LQ + quad * 8];
    s8v pf1 = *(const s8v*)&Ps[wv][lx * LQ + 32 + quad * 8];
#pragma unroll
    for (int db = 0; db < 4; ++db) {
      s8v vf0 = *(const s8v*)&Vt[(db * 16 + lx) * LQ + quad * 8];
      s8v vf1 = *(const s8v*)&Vt[(db * 16 + lx) * LQ + 32 + quad * 8];
      o_[db] = __builtin_amdgcn_mfma_f32_16x16x32_bf16(pf0, vf0, o_[db], 0, 0, 0);
      o_[db] = __builtin_amdgcn_mfma_f32_16x16x32_bf16(pf1, vf1, o_[db], 0, 0, 0);
    }
  }
#pragma unroll
  for (int r = 0; r < 4; ++r) {
    float rinv = 1.0f / l_[r];
    int row = qbase + wv * 16 + quad * 4 + r;
#pragma unroll
    for (int db = 0; db < 4; ++db)
      O[(size_t)row * DD + db * 16 + lx] = o_[db][r] * rinv;
  }
}

extern "C" void kernel_launch(void* const* d_in, const int* in_sizes, int n_in,
                              void* d_out, int out_size, void* d_ws, size_t ws_size,
                              hipStream_t stream) {
  const float* q = (const float*)d_in[0];
  const float* k = (const float*)d_in[1];
  const float* v = (const float*)d_in[2];
  float* out = (float*)d_out;

  const size_t kr_bytes = (size_t)BH * SS * DD * sizeof(short);  // 16 MB
  const size_t vt_bytes = kr_bytes;                              // 16 MB
  const size_t need = kr_bytes + vt_bytes;                       // 32 MB

  if (ws_size >= need) {
    short* kr = (short*)d_ws;
    short* vt = (short*)((char*)d_ws + kr_bytes);
    prep_kv_kernel<<<BH * NKT, NT, 0, stream>>>(k, v, kr, vt);
    attn_fast<<<dim3(BH * NKT), dim3(NT), 0, stream>>>(q, kr, vt, out);
  } else {
    attn_fallback<<<dim3(BH * NKT), dim3(NT), 0, stream>>>(q, k, v, out);
  }
}